// Round 1
// baseline (2459.764 us; speedup 1.0000x reference)
//
#include <hip/hip_runtime.h>
#include <math.h>

// SemanticDriftCoeff — fp32 baseline pipeline.
// T=4096, D=896. ws layout (floats): [0,T) invnorm, [T,2T) L, [2T,3T) dmax(uint bits),
// [3T,4T) dist, [4T,5T) gn2, [8T, 8T+T*D) g accumulator. Total ~14.2 MB.

#define T_ 4096
#define D_ 896
constexpr int BM = 16;   // rows per block tile
constexpr int BN = 32;   // s-columns per tile
constexpr int DC = 64;   // d-chunk
constexpr int NCH = D_ / DC;   // 14
constexpr int NSPLIT = 4;      // s-range split (grid y)

__device__ __forceinline__ void load_k_chunk(const float* __restrict__ x,
    const float* __restrict__ invnorm, int s0, int c0, int tid,
    float Ks[BN][DC + 4]) {
  // 32 rows x 64 cols, 8 threads/row, 8 floats/thread (two float4)
  const int kr = tid >> 3;
  const int kc = (tid & 7) * 8;
  const float inr = invnorm[s0 + kr];
  const float* src = x + (size_t)(s0 + kr) * D_ + c0 + kc;
  float4 a = *(const float4*)src;
  float4 b = *(const float4*)(src + 4);
  *(float4*)&Ks[kr][kc]     = make_float4(a.x * inr, a.y * inr, a.z * inr, a.w * inr);
  *(float4*)&Ks[kr][kc + 4] = make_float4(b.x * inr, b.y * inr, b.z * inr, b.w * inr);
}

__global__ __launch_bounds__(256) void k_rownorm(const float* __restrict__ x,
                                                 float* __restrict__ invnorm) {
  const int t = blockIdx.x;
  const int tid = threadIdx.x;
  float s = 0.f;
  const int c = tid * 4;
  if (c < D_) {
    float4 v = *(const float4*)(x + (size_t)t * D_ + c);
    s = v.x * v.x + v.y * v.y + v.z * v.z + v.w * v.w;
  }
  __shared__ float sbuf[4];
  #pragma unroll
  for (int off = 32; off > 0; off >>= 1) s += __shfl_down(s, off, 64);
  if ((tid & 63) == 0) sbuf[tid >> 6] = s;
  __syncthreads();
  if (tid == 0) {
    float tot = sbuf[0] + sbuf[1] + sbuf[2] + sbuf[3];
    invnorm[t] = 1.0f / fmaxf(sqrtf(tot), 1e-12f);
  }
}

// Loop 1: for each 16-row tile, sweep s-tiles: S = Q K^T, w = exp(S/denom) causal,
// L += rowsum(w), O += w @ K. Partials atomically accumulated into g, L.
__global__ __launch_bounds__(256) void k_loop1(const float* __restrict__ x,
    const float* __restrict__ invnorm, float* __restrict__ g, float* __restrict__ L) {
  __shared__ float Qs[BM][DC + 4];
  __shared__ float Ks[BN][DC + 4];
  __shared__ float Ws[BM][BN + 1];
  const int tau = (int)blockIdx.x;
  const int sig = (int)blockIdx.y;
  const int t0 = tau * BM;
  const int nt = (t0 + BM + BN - 1) / BN;  // s-tiles covering s <= t0+15
  if (sig >= nt) return;
  const int tid = (int)threadIdx.x;
  const int r = tid >> 4, tx = tid & 15;
  const int t = t0 + r;
  float4 O4[NCH];
  #pragma unroll
  for (int ch = 0; ch < NCH; ++ch) O4[ch] = make_float4(0.f, 0.f, 0.f, 0.f);
  float Lacc = 0.f;

  for (int st = sig; st < nt; st += NSPLIT) {
    const int s0 = st * BN;
    float S0 = 0.f, S1 = 0.f;
    for (int ch = 0; ch < NCH; ++ch) {
      __syncthreads();  // protect LDS from previous readers
      {  // Q chunk: 16x64, one float4 per thread
        const int qr = tid >> 4, qc = (tid & 15) * 4;
        const float inr = invnorm[t0 + qr];
        float4 v = *(const float4*)(x + (size_t)(t0 + qr) * D_ + ch * DC + qc);
        *(float4*)&Qs[qr][qc] = make_float4(v.x * inr, v.y * inr, v.z * inr, v.w * inr);
      }
      load_k_chunk(x, invnorm, s0, ch * DC, tid, Ks);
      __syncthreads();
      #pragma unroll
      for (int d4 = 0; d4 < DC / 4; ++d4) {
        const float4 q  = *(const float4*)&Qs[r][d4 * 4];
        const float4 k0 = *(const float4*)&Ks[tx][d4 * 4];
        const float4 k1 = *(const float4*)&Ks[tx + 16][d4 * 4];
        S0 += q.x * k0.x + q.y * k0.y + q.z * k0.z + q.w * k0.w;
        S1 += q.x * k1.x + q.y * k1.y + q.z * k1.z + q.w * k1.w;
      }
    }
    // weights: w = exp(sim / (sqrt(D)*exp(0.1*dt) + 1e-8)), causal mask dt>=0
    {
      const int dt0 = t - (s0 + tx);
      const int dt1 = dt0 - 16;
      float w0 = 0.f, w1 = 0.f;
      if (dt0 >= 0) w0 = expf(S0 / (sqrtf((float)D_) * expf(0.1f * (float)dt0) + 1e-8f));
      if (dt1 >= 0) w1 = expf(S1 / (sqrtf((float)D_) * expf(0.1f * (float)dt1) + 1e-8f));
      Ws[r][tx] = w0;
      Ws[r][tx + 16] = w1;
      Lacc += w0 + w1;
    }
    // PV sweep: O[r, ch*64 + tx*4 + i] += sum_j w[r][j] * K[j][...]
    #pragma unroll
    for (int ch = 0; ch < NCH; ++ch) {
      __syncthreads();  // also makes Ws visible on first iteration
      load_k_chunk(x, invnorm, s0, ch * DC, tid, Ks);
      __syncthreads();
      float4 acc = O4[ch];
      #pragma unroll 8
      for (int j = 0; j < BN; ++j) {
        const float wv = Ws[r][j];
        const float4 kv = *(const float4*)&Ks[j][tx * 4];
        acc.x += wv * kv.x; acc.y += wv * kv.y;
        acc.z += wv * kv.z; acc.w += wv * kv.w;
      }
      O4[ch] = acc;
    }
  }
  // epilogue: reduce L over the 16 lanes of each row, flush O partials
  float lsum = Lacc;
  #pragma unroll
  for (int off = 1; off < 16; off <<= 1) lsum += __shfl_xor(lsum, off, 64);
  if (tx == 0) atomicAdd(&L[t], lsum);
  #pragma unroll
  for (int ch = 0; ch < NCH; ++ch) {
    float* dst = g + (size_t)t * D_ + ch * DC + tx * 4;
    atomicAdd(dst + 0, O4[ch].x);
    atomicAdd(dst + 1, O4[ch].y);
    atomicAdd(dst + 2, O4[ch].z);
    atomicAdd(dst + 3, O4[ch].w);
  }
}

// Finalize: g /= L; gn2 = ||g||^2; dist = sqrt(max(||h - g||^2, 1e-24))
__global__ __launch_bounds__(256) void k_finalize(const float* __restrict__ x,
    const float* __restrict__ invnorm, float* __restrict__ g,
    const float* __restrict__ L, float* __restrict__ gn2, float* __restrict__ dist) {
  const int t = blockIdx.x;
  const int tid = threadIdx.x;
  const float invL = 1.0f / L[t];
  const float inr = invnorm[t];
  float sg = 0.f, sd = 0.f;
  const int c = tid * 4;
  if (c < D_) {
    float* gp = g + (size_t)t * D_ + c;
    float4 gv = *(float4*)gp;
    gv.x *= invL; gv.y *= invL; gv.z *= invL; gv.w *= invL;
    *(float4*)gp = gv;
    float4 hv = *(const float4*)(x + (size_t)t * D_ + c);
    hv.x *= inr; hv.y *= inr; hv.z *= inr; hv.w *= inr;
    sg = gv.x * gv.x + gv.y * gv.y + gv.z * gv.z + gv.w * gv.w;
    float dx = hv.x - gv.x, dy = hv.y - gv.y, dz = hv.z - gv.z, dw = hv.w - gv.w;
    sd = dx * dx + dy * dy + dz * dz + dw * dw;
  }
  __shared__ float sb1[4], sb2[4];
  #pragma unroll
  for (int off = 32; off > 0; off >>= 1) {
    sg += __shfl_down(sg, off, 64);
    sd += __shfl_down(sd, off, 64);
  }
  if ((tid & 63) == 0) { sb1[tid >> 6] = sg; sb2[tid >> 6] = sd; }
  __syncthreads();
  if (tid == 0) {
    gn2[t]  = sb1[0] + sb1[1] + sb1[2] + sb1[3];
    dist[t] = sqrtf(fmaxf(sb2[0] + sb2[1] + sb2[2] + sb2[3], 1e-24f));
  }
}

// Loop 2: cross = g h^T; d2 = hn2(=1) - 2*cross + gn2; causal max via uint atomicMax.
__global__ __launch_bounds__(256) void k_loop2(const float* __restrict__ x,
    const float* __restrict__ invnorm, const float* __restrict__ g,
    const float* __restrict__ gn2, unsigned int* __restrict__ dmaxu) {
  __shared__ float Gs[BM][DC + 4];
  __shared__ float Ks[BN][DC + 4];
  const int tau = (int)blockIdx.x;
  const int sig = (int)blockIdx.y;
  const int t0 = tau * BM;
  const int nt = (t0 + BM + BN - 1) / BN;
  if (sig >= nt) return;
  const int tid = (int)threadIdx.x;
  const int r = tid >> 4, tx = tid & 15;
  const int t = t0 + r;
  const float gn = gn2[t];
  float m2 = 0.f;
  for (int st = sig; st < nt; st += NSPLIT) {
    const int s0 = st * BN;
    float C0 = 0.f, C1 = 0.f;
    for (int ch = 0; ch < NCH; ++ch) {
      __syncthreads();
      {  // G chunk (already normalized by L; no invnorm scaling)
        const int qr = tid >> 4, qc = (tid & 15) * 4;
        float4 v = *(const float4*)(g + (size_t)(t0 + qr) * D_ + ch * DC + qc);
        *(float4*)&Gs[qr][qc] = v;
      }
      load_k_chunk(x, invnorm, s0, ch * DC, tid, Ks);
      __syncthreads();
      #pragma unroll
      for (int d4 = 0; d4 < DC / 4; ++d4) {
        const float4 q  = *(const float4*)&Gs[r][d4 * 4];
        const float4 k0 = *(const float4*)&Ks[tx][d4 * 4];
        const float4 k1 = *(const float4*)&Ks[tx + 16][d4 * 4];
        C0 += q.x * k0.x + q.y * k0.y + q.z * k0.z + q.w * k0.w;
        C1 += q.x * k1.x + q.y * k1.y + q.z * k1.z + q.w * k1.w;
      }
    }
    const int dt0 = t - (s0 + tx);
    const int dt1 = dt0 - 16;
    if (dt0 >= 0) m2 = fmaxf(m2, fmaxf(1.0f - 2.f * C0 + gn, 1e-24f));
    if (dt1 >= 0) m2 = fmaxf(m2, fmaxf(1.0f - 2.f * C1 + gn, 1e-24f));
  }
  #pragma unroll
  for (int off = 1; off < 16; off <<= 1) m2 = fmaxf(m2, __shfl_xor(m2, off, 64));
  // positive floats preserve order as uint bit patterns
  if (tx == 0) atomicMax(dmaxu + t, __float_as_uint(m2));
}

__global__ __launch_bounds__(256) void k_final(const float* __restrict__ m_t,
    const float* __restrict__ c_t, const float* __restrict__ d_t,
    const float* __restrict__ mu, const float* __restrict__ dist,
    const unsigned int* __restrict__ dmaxu, float* __restrict__ out) {
  const int t = (int)blockIdx.x * 256 + (int)threadIdx.x;
  if (t >= T_) return;
  float dmax = sqrtf(__uint_as_float(dmaxu[t]));
  if (dmax < 1e-6f) dmax = 1.0f;
  const float ratio = dist[t] / (dmax + 1e-8f);
  const float stab = 1.0f - 0.3f * c_t[t] + 0.2f * d_t[t];
  const float xi = 1.0f - mu[0] * m_t[t];
  out[t] = fminf(fmaxf(ratio * stab * xi, 0.f), 1.f);
}

extern "C" void kernel_launch(void* const* d_in, const int* in_sizes, int n_in,
                              void* d_out, int out_size, void* d_ws, size_t ws_size,
                              hipStream_t stream) {
  const float* x   = (const float*)d_in[0];
  const float* m_t = (const float*)d_in[1];
  const float* c_t = (const float*)d_in[2];
  const float* d_t = (const float*)d_in[3];
  const float* mu  = (const float*)d_in[4];
  float* out = (float*)d_out;

  float* ws = (float*)d_ws;
  float* invnorm = ws;                      // [T]
  float* L       = ws + T_;                 // [T]
  unsigned int* dmaxu = (unsigned int*)(ws + 2 * (size_t)T_);  // [T]
  float* dist    = ws + 3 * (size_t)T_;     // [T]
  float* gn2     = ws + 4 * (size_t)T_;     // [T]
  float* g       = ws + 8 * (size_t)T_;     // [T*D]

  // ws is poisoned 0xAA before every timed call — zero the accumulators.
  hipMemsetAsync(L, 0, 2 * (size_t)T_ * sizeof(float), stream);  // L + dmaxu
  hipMemsetAsync(g, 0, (size_t)T_ * D_ * sizeof(float), stream);

  k_rownorm<<<T_, 256, 0, stream>>>(x, invnorm);
  k_loop1<<<dim3(T_ / BM, NSPLIT), 256, 0, stream>>>(x, invnorm, g, L);
  k_finalize<<<T_, 256, 0, stream>>>(x, invnorm, g, L, gn2, dist);
  k_loop2<<<dim3(T_ / BM, NSPLIT), 256, 0, stream>>>(x, invnorm, g, gn2, dmaxu);
  k_final<<<(T_ + 255) / 256, 256, 0, stream>>>(m_t, c_t, d_t, mu, dist, dmaxu, out);
}

// Round 2
// 495.403 us; speedup vs baseline: 4.9652x; 4.9652x over previous
//
#include <hip/hip_runtime.h>
#include <math.h>

// SemanticDriftCoeff — MFMA bf16 pipeline.
// T=4096, D=896. ws (floats): [0,T) invnorm, [T,2T) L, [2T,3T) dmaxu, [3T,4T) dist,
// [4T,5T) gn2, [8T,8T+T*D) g fp32; then bf16 (ushort): hb[T*D], hbT[D*T], gb[T*D].
// Total ~36.8 MB.

#define T_ 4096
#define D_ 896
constexpr int NSPLIT = 4;   // s-range split; g accumulated by atomicAdd across sig

typedef float f32x4 __attribute__((ext_vector_type(4)));
typedef unsigned short u16x8 __attribute__((ext_vector_type(8)));
typedef __bf16 bf16x8 __attribute__((ext_vector_type(8)));

union V16 { uint4 u; u16x8 v; };

__device__ __forceinline__ u16x8 ld16(const unsigned short* p) {
  V16 x; x.u = *(const uint4*)p; return x.v;
}
__device__ __forceinline__ unsigned short f2bf(float f) {  // RNE float->bf16 bits
  unsigned int u = __float_as_uint(f);
  u += 0x7FFFu + ((u >> 16) & 1u);
  return (unsigned short)(u >> 16);
}
__device__ __forceinline__ f32x4 mfma16(u16x8 a, u16x8 b, f32x4 c) {
  return __builtin_amdgcn_mfma_f32_16x16x32_bf16(
      __builtin_bit_cast(bf16x8, a), __builtin_bit_cast(bf16x8, b), c, 0, 0, 0);
}

// ---------- prep: invnorm + bf16 normalized rows ----------
__global__ __launch_bounds__(256) void k_prep(const float* __restrict__ x,
    float* __restrict__ invnorm, unsigned short* __restrict__ hb) {
  const int t = (int)blockIdx.x, tid = (int)threadIdx.x;
  const int c = tid * 4;
  float4 v = make_float4(0.f, 0.f, 0.f, 0.f);
  float s = 0.f;
  if (c < D_) {
    v = *(const float4*)(x + t * D_ + c);
    s = v.x * v.x + v.y * v.y + v.z * v.z + v.w * v.w;
  }
  __shared__ float sb[4];
  __shared__ float sinv;
  #pragma unroll
  for (int off = 32; off > 0; off >>= 1) s += __shfl_down(s, off, 64);
  if ((tid & 63) == 0) sb[tid >> 6] = s;
  __syncthreads();
  if (tid == 0) {
    const float tot = sb[0] + sb[1] + sb[2] + sb[3];
    const float iv = 1.0f / fmaxf(sqrtf(tot), 1e-12f);
    invnorm[t] = iv; sinv = iv;
  }
  __syncthreads();
  if (c < D_) {
    const float iv = sinv;
    *(ushort4*)(hb + t * D_ + c) = make_ushort4(
        f2bf(v.x * iv), f2bf(v.y * iv), f2bf(v.z * iv), f2bf(v.w * iv));
  }
}

// ---------- 32x32 bf16 transpose hb -> hbT ----------
__global__ __launch_bounds__(256) void k_transp(const unsigned short* __restrict__ hb,
                                                unsigned short* __restrict__ hbT) {
  __shared__ unsigned short Ts[32][36];
  const int t0 = (int)blockIdx.x * 32, d0 = (int)blockIdx.y * 32;
  const int r = (int)threadIdx.x >> 3, c = ((int)threadIdx.x & 7) * 4;
  const ushort4 v = *(const ushort4*)(hb + (t0 + r) * D_ + d0 + c);
  Ts[r][c] = v.x; Ts[r][c + 1] = v.y; Ts[r][c + 2] = v.z; Ts[r][c + 3] = v.w;
  __syncthreads();
  const ushort4 o = make_ushort4(Ts[c][r], Ts[c + 1][r], Ts[c + 2][r], Ts[c + 3][r]);
  *(ushort4*)(hbT + (d0 + r) * T_ + t0 + c) = o;
}

// ---------- loop1: flash pass, S^T = K Q^T (D-split across waves), W=exp, O += W K ----------
__global__ __launch_bounds__(256, 2) void k_loop1(
    const unsigned short* __restrict__ hb, const unsigned short* __restrict__ hbT,
    float* __restrict__ g, float* __restrict__ L) {
  __shared__ float Sp[2][4][32][17];
  const int tid = (int)threadIdx.x;
  const int wv = tid >> 6, lane = tid & 63;
  const int tcol = lane & 15, quad = lane >> 4;
  const int dsl = wv * 224;              // wave's D-slice (for S^T reduction and O)
  const int p = (int)blockIdx.x, sig = (int)blockIdx.y;
  int buf = 0;
  #pragma unroll 1
  for (int half = 0; half < 2; ++half) {
    const int tau = half ? (255 - p) : p;  // triangle balancing: pair p with 255-p
    const int t0 = tau * 16;
    u16x8 qf[7];                           // B-frags: Q[t0+tcol][dsl + k*32 + quad*8 ..]
    #pragma unroll
    for (int k = 0; k < 7; ++k)
      qf[k] = ld16(hb + (t0 + tcol) * D_ + dsl + k * 32 + quad * 8);
    f32x4 O[14] = {};
    float Lacc = 0.f;
    const int nt = (t0 + 47) >> 5;         // s-tiles covering s <= t0+15
    #pragma unroll 1
    for (int st = sig; st < nt; st += NSPLIT) {
      const int s0 = st * 32;
      f32x4 c0 = {}, c1 = {};
      const unsigned short* ar = hb + (s0 + tcol) * D_ + dsl + quad * 8;
      #pragma unroll
      for (int k = 0; k < 7; ++k) {        // A-frags: K rows (s0..s0+31), wave's D-slice
        u16x8 a0 = ld16(ar + k * 32);
        u16x8 a1 = ld16(ar + 16 * D_ + k * 32);
        c0 = mfma16(a0, qf[k], c0);        // S^T[s 0..15][t] partial
        c1 = mfma16(a1, qf[k], c1);        // S^T[s 16..31][t] partial
      }
      #pragma unroll
      for (int r = 0; r < 4; ++r) {        // C-layout: col=lane&15 (t), row=quad*4+r (s)
        Sp[buf][wv][quad * 4 + r][tcol] = c0[r];
        Sp[buf][wv][16 + quad * 4 + r][tcol] = c1[r];
      }
      __syncthreads();
      u16x8 wf;                            // A-frag for PV: W[t=tcol][s=quad*8+j]
      #pragma unroll
      for (int j = 0; j < 8; ++j) {
        const int sl = quad * 8 + j;
        const float S = Sp[buf][0][sl][tcol] + Sp[buf][1][sl][tcol] +
                        Sp[buf][2][sl][tcol] + Sp[buf][3][sl][tcol];
        const int dt = (t0 + tcol) - (s0 + sl);
        float wj = 0.f;
        // 1/(sqrt(D)*e^{.1dt}+1e-8) == e^{-.1dt}/sqrt(D) to 3e-10; matches inf/underflow ends
        if (dt >= 0) wj = __expf(S * (__expf(-0.1f * (float)dt) * 0.033407657f));
        const unsigned short wb = f2bf(wj);
        wf[j] = wb;
        if (wv == 0) Lacc += __uint_as_float(((unsigned int)wb) << 16);  // L = sum of bf16(w)
      }
      const unsigned short* br = hbT + (dsl + tcol) * T_ + s0 + quad * 8;
      #pragma unroll
      for (int n = 0; n < 14; ++n) {       // B-frags from hbT: h[s0+quad*8+j][dsl+n*16+tcol]
        u16x8 b = ld16(br + n * 16 * T_);
        O[n] = mfma16(wf, b, O[n]);        // O[t][d] += W[t][s] h[s][d]
      }
      buf ^= 1;
    }
    if (wv == 0) {
      float l = Lacc;
      l += __shfl_xor(l, 16, 64);
      l += __shfl_xor(l, 32, 64);
      if (lane < 16) atomicAdd(&L[t0 + lane], l);
    }
    #pragma unroll
    for (int n = 0; n < 14; ++n) {         // C-layout: col=d-offset, row=t-offset
      float* gr = g + (t0 + quad * 4) * D_ + dsl + n * 16 + tcol;
      atomicAdd(gr, O[n][0]);
      atomicAdd(gr + D_, O[n][1]);
      atomicAdd(gr + 2 * D_, O[n][2]);
      atomicAdd(gr + 3 * D_, O[n][3]);
    }
  }
}

// ---------- finalize: g/=L, gn2, dist, gb=bf16(g) ----------
__global__ __launch_bounds__(256) void k_finalize(const float* __restrict__ x,
    const float* __restrict__ invnorm, const float* __restrict__ g,
    const float* __restrict__ L, float* __restrict__ gn2, float* __restrict__ dist,
    unsigned short* __restrict__ gb) {
  const int t = (int)blockIdx.x, tid = (int)threadIdx.x;
  const float invL = 1.0f / L[t];
  const float inr = invnorm[t];
  float sg = 0.f, sd = 0.f;
  const int c = tid * 4;
  if (c < D_) {
    float4 gv = *(const float4*)(g + t * D_ + c);
    gv.x *= invL; gv.y *= invL; gv.z *= invL; gv.w *= invL;
    *(ushort4*)(gb + t * D_ + c) = make_ushort4(f2bf(gv.x), f2bf(gv.y), f2bf(gv.z), f2bf(gv.w));
    float4 hv = *(const float4*)(x + t * D_ + c);
    hv.x *= inr; hv.y *= inr; hv.z *= inr; hv.w *= inr;
    sg = gv.x * gv.x + gv.y * gv.y + gv.z * gv.z + gv.w * gv.w;
    const float dx = hv.x - gv.x, dy = hv.y - gv.y, dz = hv.z - gv.z, dw = hv.w - gv.w;
    sd = dx * dx + dy * dy + dz * dz + dw * dw;
  }
  __shared__ float sb1[4], sb2[4];
  #pragma unroll
  for (int off = 32; off > 0; off >>= 1) {
    sg += __shfl_down(sg, off, 64);
    sd += __shfl_down(sd, off, 64);
  }
  if ((tid & 63) == 0) { sb1[tid >> 6] = sg; sb2[tid >> 6] = sd; }
  __syncthreads();
  if (tid == 0) {
    gn2[t]  = sb1[0] + sb1[1] + sb1[2] + sb1[3];
    dist[t] = sqrtf(fmaxf(sb2[0] + sb2[1] + sb2[2] + sb2[3], 1e-24f));
  }
}

// ---------- loop2: C^T = h g^T (D-split), d2 = 1 - 2C + gn2, causal row-max ----------
__global__ __launch_bounds__(256, 2) void k_loop2(
    const unsigned short* __restrict__ hb, const unsigned short* __restrict__ gb,
    const float* __restrict__ gn2, unsigned int* __restrict__ dmaxu) {
  __shared__ float Sp[2][4][32][17];
  const int tid = (int)threadIdx.x;
  const int wv = tid >> 6, lane = tid & 63;
  const int tcol = lane & 15, quad = lane >> 4;
  const int dsl = wv * 224;
  const int p = (int)blockIdx.x, sig = (int)blockIdx.y;
  int buf = 0;
  #pragma unroll 1
  for (int half = 0; half < 2; ++half) {
    const int tau = half ? (255 - p) : p;
    const int t0 = tau * 16;
    u16x8 gf[7];
    #pragma unroll
    for (int k = 0; k < 7; ++k)
      gf[k] = ld16(gb + (t0 + tcol) * D_ + dsl + k * 32 + quad * 8);
    const float gnt = gn2[t0 + tcol];
    float m2 = 0.f;
    const int nt = (t0 + 47) >> 5;
    #pragma unroll 1
    for (int st = sig; st < nt; st += NSPLIT) {
      const int s0 = st * 32;
      f32x4 c0 = {}, c1 = {};
      const unsigned short* ar = hb + (s0 + tcol) * D_ + dsl + quad * 8;
      #pragma unroll
      for (int k = 0; k < 7; ++k) {
        u16x8 a0 = ld16(ar + k * 32);
        u16x8 a1 = ld16(ar + 16 * D_ + k * 32);
        c0 = mfma16(a0, gf[k], c0);
        c1 = mfma16(a1, gf[k], c1);
      }
      #pragma unroll
      for (int r = 0; r < 4; ++r) {
        Sp[buf][wv][quad * 4 + r][tcol] = c0[r];
        Sp[buf][wv][16 + quad * 4 + r][tcol] = c1[r];
      }
      __syncthreads();
      #pragma unroll
      for (int j = 0; j < 8; ++j) {
        const int sl = quad * 8 + j;
        const float C = Sp[buf][0][sl][tcol] + Sp[buf][1][sl][tcol] +
                        Sp[buf][2][sl][tcol] + Sp[buf][3][sl][tcol];
        const int dt = (t0 + tcol) - (s0 + sl);
        if (dt >= 0) m2 = fmaxf(m2, fmaxf(1.0f - 2.0f * C + gnt, 1e-24f));
      }
      buf ^= 1;
    }
    m2 = fmaxf(m2, __shfl_xor(m2, 16, 64));
    m2 = fmaxf(m2, __shfl_xor(m2, 32, 64));
    if (wv == 0 && lane < 16) atomicMax(&dmaxu[t0 + lane], __float_as_uint(m2));
  }
}

__global__ __launch_bounds__(256) void k_final(const float* __restrict__ m_t,
    const float* __restrict__ c_t, const float* __restrict__ d_t,
    const float* __restrict__ mu, const float* __restrict__ dist,
    const unsigned int* __restrict__ dmaxu, float* __restrict__ out) {
  const int t = (int)blockIdx.x * 256 + (int)threadIdx.x;
  if (t >= T_) return;
  float ratio;
  if (t == 0) {
    ratio = 0.f;  // ref: dist=1e-12, dist_max<1e-6 -> 1.0 => ratio ~1e-12 (bf16 path can't see this)
  } else {
    float dmax = sqrtf(__uint_as_float(dmaxu[t]));
    if (dmax < 1e-6f) dmax = 1.0f;
    ratio = dist[t] / (dmax + 1e-8f);
  }
  const float stab = 1.0f - 0.3f * c_t[t] + 0.2f * d_t[t];
  const float xi = 1.0f - mu[0] * m_t[t];
  out[t] = fminf(fmaxf(ratio * stab * xi, 0.f), 1.f);
}

extern "C" void kernel_launch(void* const* d_in, const int* in_sizes, int n_in,
                              void* d_out, int out_size, void* d_ws, size_t ws_size,
                              hipStream_t stream) {
  const float* x   = (const float*)d_in[0];
  const float* m_t = (const float*)d_in[1];
  const float* c_t = (const float*)d_in[2];
  const float* d_t = (const float*)d_in[3];
  const float* mu  = (const float*)d_in[4];
  float* out = (float*)d_out;

  float* ws = (float*)d_ws;
  float* invnorm = ws;                                         // [T]
  float* L       = ws + T_;                                    // [T]
  unsigned int* dmaxu = (unsigned int*)(ws + 2 * (size_t)T_);  // [T]
  float* dist    = ws + 3 * (size_t)T_;                        // [T]
  float* gn2     = ws + 4 * (size_t)T_;                        // [T]
  float* g       = ws + 8 * (size_t)T_;                        // [T*D] fp32
  unsigned short* hb  = (unsigned short*)(ws + 8 * (size_t)T_ + (size_t)T_ * D_);
  unsigned short* hbT = hb + (size_t)T_ * D_;
  unsigned short* gb  = hbT + (size_t)T_ * D_;

  hipMemsetAsync(L, 0, 2 * (size_t)T_ * sizeof(float), stream);   // L + dmaxu
  hipMemsetAsync(g, 0, (size_t)T_ * D_ * sizeof(float), stream);

  k_prep<<<T_, 256, 0, stream>>>(x, invnorm, hb);
  k_transp<<<dim3(T_ / 32, D_ / 32), 256, 0, stream>>>(hb, hbT);
  k_loop1<<<dim3(128, NSPLIT), 256, 0, stream>>>(hb, hbT, g, L);
  k_finalize<<<T_, 256, 0, stream>>>(x, invnorm, g, L, gn2, dist, gb);
  k_loop2<<<dim3(128, NSPLIT), 256, 0, stream>>>(hb, gb, gn2, dmaxu);
  k_final<<<(T_ + 255) / 256, 256, 0, stream>>>(m_t, c_t, d_t, mu, dist, dmaxu, out);
}

// Round 3
// 272.899 us; speedup vs baseline: 9.0135x; 1.8153x over previous
//
#include <hip/hip_runtime.h>
#include <math.h>

// SemanticDriftCoeff — three m97-style LDS-staged bf16 MFMA GEMMs with
// materialized causal weight matrix W (bf16).
// ws layout: floats [0,T) invnorm, [T,2T) L, [2T,3T) dmaxu, [3T,4T) gn2,
// [4T,5T) dist2; then ushort hb[T*D], hbT[D*T], gb[T*D], W[T*T]. ~55.7 MB.

#define T_ 4096
#define D_ 896

typedef float f32x4 __attribute__((ext_vector_type(4)));
typedef unsigned short u16x8 __attribute__((ext_vector_type(8)));
typedef __bf16 bf16x8 __attribute__((ext_vector_type(8)));

union V16 { uint4 u; u16x8 v; };

__device__ __forceinline__ u16x8 ld16(const unsigned short* p) {
  V16 x; x.u = *(const uint4*)p; return x.v;
}
__device__ __forceinline__ unsigned short f2bf(float f) {  // RNE float->bf16 bits
  unsigned int u = __float_as_uint(f);
  u += 0x7FFFu + ((u >> 16) & 1u);
  return (unsigned short)(u >> 16);
}
__device__ __forceinline__ float bf2f(unsigned short b) {
  return __uint_as_float(((unsigned int)b) << 16);
}
__device__ __forceinline__ f32x4 mfma16(u16x8 a, u16x8 b, f32x4 c) {
  return __builtin_amdgcn_mfma_f32_16x16x32_bf16(
      __builtin_bit_cast(bf16x8, a), __builtin_bit_cast(bf16x8, b), c, 0, 0, 0);
}

typedef __attribute__((address_space(1))) const void glob_cv;
typedef __attribute__((address_space(3))) void lds_v;
__device__ __forceinline__ void gload16(const void* g, void* l) {
  __builtin_amdgcn_global_load_lds((glob_cv*)g, (lds_v*)l, 16, 0, 0);
}

// Stage a 128x64 bf16 tile (rows at `stride` ushorts) into contiguous LDS [128][64].
// 256 threads x 4 issues x 16 B; LDS dst is contiguous in lane order (wave-uniform
// base + lane*16 — the global_load_lds constraint), so NO padding.
__device__ __forceinline__ void stage_tile(const unsigned short* __restrict__ g0,
                                           int stride, unsigned short* lds0, int tid) {
  #pragma unroll
  for (int it = 0; it < 4; ++it) {
    const int e = (it * 256 + tid) * 8;          // ushort index in tile
    const int row = e >> 6, col = e & 63;
    gload16(g0 + (size_t)row * stride + col, lds0 + e);
  }
}

// ---------- prep: invnorm + bf16 normalized rows ----------
__global__ __launch_bounds__(256) void k_prep(const float* __restrict__ x,
    float* __restrict__ invnorm, unsigned short* __restrict__ hb) {
  const int t = (int)blockIdx.x, tid = (int)threadIdx.x;
  const int c = tid * 4;
  float4 v = make_float4(0.f, 0.f, 0.f, 0.f);
  float s = 0.f;
  if (c < D_) {
    v = *(const float4*)(x + (size_t)t * D_ + c);
    s = v.x * v.x + v.y * v.y + v.z * v.z + v.w * v.w;
  }
  __shared__ float sb[4];
  __shared__ float sinv;
  #pragma unroll
  for (int off = 32; off > 0; off >>= 1) s += __shfl_down(s, off, 64);
  if ((tid & 63) == 0) sb[tid >> 6] = s;
  __syncthreads();
  if (tid == 0) {
    const float tot = sb[0] + sb[1] + sb[2] + sb[3];
    const float iv = 1.0f / fmaxf(sqrtf(tot), 1e-12f);
    invnorm[t] = iv; sinv = iv;
  }
  __syncthreads();
  if (c < D_) {
    const float iv = sinv;
    *(ushort4*)(hb + (size_t)t * D_ + c) = make_ushort4(
        f2bf(v.x * iv), f2bf(v.y * iv), f2bf(v.z * iv), f2bf(v.w * iv));
  }
}

// ---------- 32x32 bf16 transpose hb -> hbT ----------
__global__ __launch_bounds__(256) void k_transp(const unsigned short* __restrict__ hb,
                                                unsigned short* __restrict__ hbT) {
  __shared__ unsigned short Ts[32][36];
  const int t0 = (int)blockIdx.x * 32, d0 = (int)blockIdx.y * 32;
  const int r = (int)threadIdx.x >> 3, c = ((int)threadIdx.x & 7) * 4;
  const ushort4 v = *(const ushort4*)(hb + (size_t)(t0 + r) * D_ + d0 + c);
  Ts[r][c] = v.x; Ts[r][c + 1] = v.y; Ts[r][c + 2] = v.z; Ts[r][c + 3] = v.w;
  __syncthreads();
  const ushort4 o = make_ushort4(Ts[c][r], Ts[c + 1][r], Ts[c + 2][r], Ts[c + 3][r]);
  *(ushort4*)(hbT + (size_t)(d0 + r) * T_ + t0 + c) = o;
}

// ---------- GEMM1: S = h h^T (causal tiles); epilogue W = exp, L = rowsum ----------
__global__ __launch_bounds__(256) void k_gemm1(const unsigned short* __restrict__ hb,
    unsigned short* __restrict__ W, float* __restrict__ L) {
  const int ti = (int)blockIdx.x, sj = (int)blockIdx.y;
  if (sj > ti) return;
  const int t0 = ti * 128, s0 = sj * 128;
  __shared__ unsigned short As[128 * 64];
  __shared__ unsigned short Bs[128 * 64];
  const int tid = (int)threadIdx.x;
  const int lane = tid & 63, wv = tid >> 6;
  const int wm = wv >> 1, wn = wv & 1;
  const int tcol = lane & 15, quad = lane >> 4;
  f32x4 acc[4][4] = {};
  for (int kc = 0; kc < 14; ++kc) {
    __syncthreads();
    stage_tile(hb + (size_t)t0 * D_ + kc * 64, D_, As, tid);
    stage_tile(hb + (size_t)s0 * D_ + kc * 64, D_, Bs, tid);
    __syncthreads();
    #pragma unroll
    for (int kk = 0; kk < 2; ++kk) {
      u16x8 af[4], bf[4];
      #pragma unroll
      for (int mi = 0; mi < 4; ++mi)
        af[mi] = ld16(&As[(wm * 64 + mi * 16 + tcol) * 64 + kk * 32 + quad * 8]);
      #pragma unroll
      for (int ni = 0; ni < 4; ++ni)
        bf[ni] = ld16(&Bs[(wn * 64 + ni * 16 + tcol) * 64 + kk * 32 + quad * 8]);
      #pragma unroll
      for (int mi = 0; mi < 4; ++mi)
        #pragma unroll
        for (int ni = 0; ni < 4; ++ni)
          acc[mi][ni] = mfma16(af[mi], bf[ni], acc[mi][ni]);
    }
  }
  // epilogue: w = exp(S * e^{-0.1 dt} / sqrt(D)) for dt>=0, else 0
  #pragma unroll
  for (int mi = 0; mi < 4; ++mi) {
    #pragma unroll
    for (int r = 0; r < 4; ++r) {
      const int t = t0 + wm * 64 + mi * 16 + quad * 4 + r;
      float lsum = 0.f;
      #pragma unroll
      for (int ni = 0; ni < 4; ++ni) {
        const int s = s0 + wn * 64 + ni * 16 + tcol;
        const int dt = t - s;
        float wval = 0.f;
        if (dt >= 0)
          wval = __expf(acc[mi][ni][r] * (__expf(-0.1f * (float)dt) * 0.033407657f));
        const unsigned short wb = f2bf(wval);
        W[(size_t)t * T_ + s] = wb;
        lsum += bf2f(wb);
      }
      lsum += __shfl_xor(lsum, 1, 64);
      lsum += __shfl_xor(lsum, 2, 64);
      lsum += __shfl_xor(lsum, 4, 64);
      lsum += __shfl_xor(lsum, 8, 64);
      if (tcol == 0) atomicAdd(&L[t], lsum);
    }
  }
}

// ---------- GEMM2: gT[d][t] = sum_s hbT[d][s] W[t][s]; epilogue /L, gb, gn2, dist2 ----------
__global__ __launch_bounds__(256) void k_gemm2(const unsigned short* __restrict__ hbT,
    const unsigned short* __restrict__ W, const float* __restrict__ x,
    const float* __restrict__ invnorm, const float* __restrict__ L,
    unsigned short* __restrict__ gb, float* __restrict__ gn2, float* __restrict__ dist2) {
  const int di = (int)blockIdx.x, tj = (int)blockIdx.y;
  const int d0 = di * 128, t0 = tj * 128;
  __shared__ unsigned short As[128 * 64];
  __shared__ unsigned short Bs[128 * 64];
  const int tid = (int)threadIdx.x;
  const int lane = tid & 63, wv = tid >> 6;
  const int wm = wv >> 1, wn = wv & 1;
  const int tcol = lane & 15, quad = lane >> 4;
  f32x4 acc[4][4] = {};
  const int nk = 2 * (tj + 1);  // causal K range: s < t0+128
  for (int kc = 0; kc < nk; ++kc) {
    __syncthreads();
    stage_tile(hbT + (size_t)d0 * T_ + kc * 64, T_, As, tid);
    stage_tile(W + (size_t)t0 * T_ + kc * 64, T_, Bs, tid);
    __syncthreads();
    #pragma unroll
    for (int kk = 0; kk < 2; ++kk) {
      u16x8 af[4], bf[4];
      #pragma unroll
      for (int mi = 0; mi < 4; ++mi)
        af[mi] = ld16(&As[(wm * 64 + mi * 16 + tcol) * 64 + kk * 32 + quad * 8]);
      #pragma unroll
      for (int ni = 0; ni < 4; ++ni)
        bf[ni] = ld16(&Bs[(wn * 64 + ni * 16 + tcol) * 64 + kk * 32 + quad * 8]);
      #pragma unroll
      for (int mi = 0; mi < 4; ++mi)
        #pragma unroll
        for (int ni = 0; ni < 4; ++ni)
          acc[mi][ni] = mfma16(af[mi], bf[ni], acc[mi][ni]);
    }
  }
  #pragma unroll
  for (int ni = 0; ni < 4; ++ni) {
    const int t = t0 + wn * 64 + ni * 16 + tcol;
    const float invL = 1.0f / L[t];
    const float inr = invnorm[t];
    float sg = 0.f, sd = 0.f;
    #pragma unroll
    for (int mi = 0; mi < 4; ++mi) {
      const int d = d0 + wm * 64 + mi * 16 + quad * 4;
      const float g0v = acc[mi][ni][0] * invL;
      const float g1v = acc[mi][ni][1] * invL;
      const float g2v = acc[mi][ni][2] * invL;
      const float g3v = acc[mi][ni][3] * invL;
      *(ushort4*)(gb + (size_t)t * D_ + d) =
          make_ushort4(f2bf(g0v), f2bf(g1v), f2bf(g2v), f2bf(g3v));
      const float4 hv = *(const float4*)(x + (size_t)t * D_ + d);
      const float e0 = hv.x * inr - g0v, e1 = hv.y * inr - g1v;
      const float e2 = hv.z * inr - g2v, e3 = hv.w * inr - g3v;
      sg += g0v * g0v + g1v * g1v + g2v * g2v + g3v * g3v;
      sd += e0 * e0 + e1 * e1 + e2 * e2 + e3 * e3;
    }
    sg += __shfl_xor(sg, 16, 64); sg += __shfl_xor(sg, 32, 64);
    sd += __shfl_xor(sd, 16, 64); sd += __shfl_xor(sd, 32, 64);
    if (quad == 0) { atomicAdd(&gn2[t], sg); atomicAdd(&dist2[t], sd); }
  }
}

// ---------- GEMM3: cross = g h^T (causal tiles); epilogue causal row-max of d2 ----------
__global__ __launch_bounds__(256) void k_gemm3(const unsigned short* __restrict__ gb,
    const unsigned short* __restrict__ hb, const float* __restrict__ gn2,
    unsigned int* __restrict__ dmaxu) {
  const int ti = (int)blockIdx.x, sj = (int)blockIdx.y;
  if (sj > ti) return;
  const int t0 = ti * 128, s0 = sj * 128;
  __shared__ unsigned short As[128 * 64];
  __shared__ unsigned short Bs[128 * 64];
  const int tid = (int)threadIdx.x;
  const int lane = tid & 63, wv = tid >> 6;
  const int wm = wv >> 1, wn = wv & 1;
  const int tcol = lane & 15, quad = lane >> 4;
  f32x4 acc[4][4] = {};
  for (int kc = 0; kc < 14; ++kc) {
    __syncthreads();
    stage_tile(gb + (size_t)t0 * D_ + kc * 64, D_, As, tid);
    stage_tile(hb + (size_t)s0 * D_ + kc * 64, D_, Bs, tid);
    __syncthreads();
    #pragma unroll
    for (int kk = 0; kk < 2; ++kk) {
      u16x8 af[4], bf[4];
      #pragma unroll
      for (int mi = 0; mi < 4; ++mi)
        af[mi] = ld16(&As[(wm * 64 + mi * 16 + tcol) * 64 + kk * 32 + quad * 8]);
      #pragma unroll
      for (int ni = 0; ni < 4; ++ni)
        bf[ni] = ld16(&Bs[(wn * 64 + ni * 16 + tcol) * 64 + kk * 32 + quad * 8]);
      #pragma unroll
      for (int mi = 0; mi < 4; ++mi)
        #pragma unroll
        for (int ni = 0; ni < 4; ++ni)
          acc[mi][ni] = mfma16(af[mi], bf[ni], acc[mi][ni]);
    }
  }
  #pragma unroll
  for (int mi = 0; mi < 4; ++mi) {
    #pragma unroll
    for (int r = 0; r < 4; ++r) {
      const int t = t0 + wm * 64 + mi * 16 + quad * 4 + r;
      const float gn = gn2[t];
      float m2 = 0.f;
      #pragma unroll
      for (int ni = 0; ni < 4; ++ni) {
        const int s = s0 + wn * 64 + ni * 16 + tcol;
        if (t - s >= 0)
          m2 = fmaxf(m2, fmaxf(1.0f - 2.0f * acc[mi][ni][r] + gn, 1e-24f));
      }
      m2 = fmaxf(m2, __shfl_xor(m2, 1, 64));
      m2 = fmaxf(m2, __shfl_xor(m2, 2, 64));
      m2 = fmaxf(m2, __shfl_xor(m2, 4, 64));
      m2 = fmaxf(m2, __shfl_xor(m2, 8, 64));
      if (tcol == 0) atomicMax(&dmaxu[t], __float_as_uint(m2));
    }
  }
}

__global__ __launch_bounds__(256) void k_final(const float* __restrict__ m_t,
    const float* __restrict__ c_t, const float* __restrict__ d_t,
    const float* __restrict__ mu, const float* __restrict__ dist2,
    const unsigned int* __restrict__ dmaxu, float* __restrict__ out) {
  const int t = (int)blockIdx.x * 256 + (int)threadIdx.x;
  if (t >= T_) return;
  float ratio;
  if (t == 0) {
    ratio = 0.f;  // ref: dist~1e-12, dist_max<1e-6 -> 1.0 => ratio ~0
  } else {
    float dmax = sqrtf(__uint_as_float(dmaxu[t]));  // max of d2 -> sqrt
    if (dmax < 1e-6f) dmax = 1.0f;
    ratio = sqrtf(fmaxf(dist2[t], 1e-24f)) / (dmax + 1e-8f);
  }
  const float stab = 1.0f - 0.3f * c_t[t] + 0.2f * d_t[t];
  const float xi = 1.0f - mu[0] * m_t[t];
  out[t] = fminf(fmaxf(ratio * stab * xi, 0.f), 1.f);
}

extern "C" void kernel_launch(void* const* d_in, const int* in_sizes, int n_in,
                              void* d_out, int out_size, void* d_ws, size_t ws_size,
                              hipStream_t stream) {
  const float* x   = (const float*)d_in[0];
  const float* m_t = (const float*)d_in[1];
  const float* c_t = (const float*)d_in[2];
  const float* d_t = (const float*)d_in[3];
  const float* mu  = (const float*)d_in[4];
  float* out = (float*)d_out;

  float* ws = (float*)d_ws;
  float* invnorm = ws;                                         // [T]
  float* L       = ws + T_;                                    // [T]
  unsigned int* dmaxu = (unsigned int*)(ws + 2 * (size_t)T_);  // [T]
  float* gn2     = ws + 3 * (size_t)T_;                        // [T]
  float* dist2   = ws + 4 * (size_t)T_;                        // [T]
  unsigned short* hb  = (unsigned short*)(ws + 5 * (size_t)T_);
  unsigned short* hbT = hb + (size_t)T_ * D_;
  unsigned short* gb  = hbT + (size_t)T_ * D_;
  unsigned short* W   = gb + (size_t)T_ * D_;                  // [T*T] bf16

  // zero L, dmaxu, gn2, dist2 (contiguous 4T floats)
  hipMemsetAsync(L, 0, 4 * (size_t)T_ * sizeof(float), stream);

  k_prep<<<T_, 256, 0, stream>>>(x, invnorm, hb);
  k_transp<<<dim3(T_ / 32, D_ / 32), 256, 0, stream>>>(hb, hbT);
  k_gemm1<<<dim3(32, 32), 256, 0, stream>>>(hb, W, L);
  k_gemm2<<<dim3(7, 32), 256, 0, stream>>>(hbT, W, x, invnorm, L, gb, gn2, dist2);
  k_gemm3<<<dim3(32, 32), 256, 0, stream>>>(gb, hb, gn2, dmaxu);
  k_final<<<(T_ + 255) / 256, 256, 0, stream>>>(m_t, c_t, d_t, mu, dist2, dmaxu, out);
}

// Round 4
// 272.554 us; speedup vs baseline: 9.0249x; 1.0013x over previous
//
#include <hip/hip_runtime.h>
#include <math.h>

// SemanticDriftCoeff — bf16 MFMA GEMM pipeline, split-K gemm2.
// ws layout: floats [0,T) invnorm, [T,2T) L, [2T,3T) dmaxu, [3T,4T) gn2,
// [4T,5T) dist2, [5T, 5T+T*D) gacc fp32; then ushort hb[T*D], hbT[D*T],
// gb[T*D], W[T*T]. ~70.4 MB.

#define T_ 4096
#define D_ 896

typedef float f32x4 __attribute__((ext_vector_type(4)));
typedef unsigned short u16x8 __attribute__((ext_vector_type(8)));
typedef __bf16 bf16x8 __attribute__((ext_vector_type(8)));

union V16 { uint4 u; u16x8 v; };

__device__ __forceinline__ u16x8 ld16(const unsigned short* p) {
  V16 x; x.u = *(const uint4*)p; return x.v;
}
__device__ __forceinline__ unsigned short f2bf(float f) {  // RNE float->bf16 bits
  unsigned int u = __float_as_uint(f);
  u += 0x7FFFu + ((u >> 16) & 1u);
  return (unsigned short)(u >> 16);
}
__device__ __forceinline__ float bf2f(unsigned short b) {
  return __uint_as_float(((unsigned int)b) << 16);
}
__device__ __forceinline__ f32x4 mfma16(u16x8 a, u16x8 b, f32x4 c) {
  return __builtin_amdgcn_mfma_f32_16x16x32_bf16(
      __builtin_bit_cast(bf16x8, a), __builtin_bit_cast(bf16x8, b), c, 0, 0, 0);
}

typedef __attribute__((address_space(1))) const void glob_cv;
typedef __attribute__((address_space(3))) void lds_v;
__device__ __forceinline__ void gload16(const void* g, void* l) {
  __builtin_amdgcn_global_load_lds((glob_cv*)g, (lds_v*)l, 16, 0, 0);
}

// Stage a 128x64 bf16 tile (rows at `stride` ushorts) into contiguous LDS [128][64].
__device__ __forceinline__ void stage_tile(const unsigned short* __restrict__ g0,
                                           int stride, unsigned short* lds0, int tid) {
  #pragma unroll
  for (int it = 0; it < 4; ++it) {
    const int e = (it * 256 + tid) * 8;
    const int row = e >> 6, col = e & 63;
    gload16(g0 + (size_t)row * stride + col, lds0 + e);
  }
}

// triangular decode: b -> (ti, sj), sj <= ti
__device__ __forceinline__ void tri_decode(int b, int& ti, int& sj) {
  ti = (int)((sqrtf(8.0f * (float)b + 1.0f) - 1.0f) * 0.5f);
  while ((ti + 1) * (ti + 2) / 2 <= b) ++ti;
  while (ti * (ti + 1) / 2 > b) --ti;
  sj = b - ti * (ti + 1) / 2;
}

// ---------- prep: invnorm + bf16 normalized rows ----------
__global__ __launch_bounds__(256) void k_prep(const float* __restrict__ x,
    float* __restrict__ invnorm, unsigned short* __restrict__ hb) {
  const int t = (int)blockIdx.x, tid = (int)threadIdx.x;
  const int c = tid * 4;
  float4 v = make_float4(0.f, 0.f, 0.f, 0.f);
  float s = 0.f;
  if (c < D_) {
    v = *(const float4*)(x + (size_t)t * D_ + c);
    s = v.x * v.x + v.y * v.y + v.z * v.z + v.w * v.w;
  }
  __shared__ float sb[4];
  __shared__ float sinv;
  #pragma unroll
  for (int off = 32; off > 0; off >>= 1) s += __shfl_down(s, off, 64);
  if ((tid & 63) == 0) sb[tid >> 6] = s;
  __syncthreads();
  if (tid == 0) {
    const float tot = sb[0] + sb[1] + sb[2] + sb[3];
    const float iv = 1.0f / fmaxf(sqrtf(tot), 1e-12f);
    invnorm[t] = iv; sinv = iv;
  }
  __syncthreads();
  if (c < D_) {
    const float iv = sinv;
    *(ushort4*)(hb + (size_t)t * D_ + c) = make_ushort4(
        f2bf(v.x * iv), f2bf(v.y * iv), f2bf(v.z * iv), f2bf(v.w * iv));
  }
}

// ---------- 32x32 bf16 transpose hb -> hbT ----------
__global__ __launch_bounds__(256) void k_transp(const unsigned short* __restrict__ hb,
                                                unsigned short* __restrict__ hbT) {
  __shared__ unsigned short Ts[32][36];
  const int t0 = (int)blockIdx.x * 32, d0 = (int)blockIdx.y * 32;
  const int r = (int)threadIdx.x >> 3, c = ((int)threadIdx.x & 7) * 4;
  const ushort4 v = *(const ushort4*)(hb + (size_t)(t0 + r) * D_ + d0 + c);
  Ts[r][c] = v.x; Ts[r][c + 1] = v.y; Ts[r][c + 2] = v.z; Ts[r][c + 3] = v.w;
  __syncthreads();
  const ushort4 o = make_ushort4(Ts[c][r], Ts[c + 1][r], Ts[c + 2][r], Ts[c + 3][r]);
  *(ushort4*)(hbT + (size_t)(d0 + r) * T_ + t0 + c) = o;
}

// ---------- GEMM1: S = h h^T (528 causal tiles); epilogue W = exp, L = rowsum ----------
__global__ __launch_bounds__(256) void k_gemm1(const unsigned short* __restrict__ hb,
    unsigned short* __restrict__ W, float* __restrict__ L) {
  int ti, sj;
  tri_decode((int)blockIdx.x, ti, sj);
  const int t0 = ti * 128, s0 = sj * 128;
  __shared__ unsigned short As[128 * 64];
  __shared__ unsigned short Bs[128 * 64];
  const int tid = (int)threadIdx.x;
  const int lane = tid & 63, wv = tid >> 6;
  const int wm = wv >> 1, wn = wv & 1;
  const int tcol = lane & 15, quad = lane >> 4;
  f32x4 acc[4][4] = {};
  for (int kc = 0; kc < 14; ++kc) {
    __syncthreads();
    stage_tile(hb + (size_t)t0 * D_ + kc * 64, D_, As, tid);
    stage_tile(hb + (size_t)s0 * D_ + kc * 64, D_, Bs, tid);
    __syncthreads();
    #pragma unroll
    for (int kk = 0; kk < 2; ++kk) {
      u16x8 af[4], bf[4];
      #pragma unroll
      for (int mi = 0; mi < 4; ++mi)
        af[mi] = ld16(&As[(wm * 64 + mi * 16 + tcol) * 64 + kk * 32 + quad * 8]);
      #pragma unroll
      for (int ni = 0; ni < 4; ++ni)
        bf[ni] = ld16(&Bs[(wn * 64 + ni * 16 + tcol) * 64 + kk * 32 + quad * 8]);
      #pragma unroll
      for (int mi = 0; mi < 4; ++mi)
        #pragma unroll
        for (int ni = 0; ni < 4; ++ni)
          acc[mi][ni] = mfma16(af[mi], bf[ni], acc[mi][ni]);
    }
  }
  #pragma unroll
  for (int mi = 0; mi < 4; ++mi) {
    #pragma unroll
    for (int r = 0; r < 4; ++r) {
      const int t = t0 + wm * 64 + mi * 16 + quad * 4 + r;
      float lsum = 0.f;
      #pragma unroll
      for (int ni = 0; ni < 4; ++ni) {
        const int s = s0 + wn * 64 + ni * 16 + tcol;
        const int dt = t - s;
        float wval = 0.f;
        if (dt >= 0)
          wval = __expf(acc[mi][ni][r] * (__expf(-0.1f * (float)dt) * 0.033407657f));
        const unsigned short wb = f2bf(wval);
        W[(size_t)t * T_ + s] = wb;
        lsum += bf2f(wb);
      }
      lsum += __shfl_xor(lsum, 1, 64);
      lsum += __shfl_xor(lsum, 2, 64);
      lsum += __shfl_xor(lsum, 4, 64);
      lsum += __shfl_xor(lsum, 8, 64);
      if (tcol == 0) atomicAdd(&L[t], lsum);
    }
  }
}

// ---------- GEMM2 (split-K): gacc[t][d] += sum_s W[t][s] hbT[d][s] ----------
__global__ __launch_bounds__(256) void k_gemm2(const unsigned short* __restrict__ W,
    const unsigned short* __restrict__ hbT, float* __restrict__ gacc) {
  const int tj = (int)blockIdx.x, dj = (int)blockIdx.y, z = (int)blockIdx.z;
  const int nk = 2 * (tj + 1);          // causal chunks: s < t0+128
  const int k0 = z * 8;
  if (k0 >= nk) return;
  const int k1 = min(k0 + 8, nk);
  const int t0 = tj * 128, d0 = dj * 128;
  __shared__ unsigned short As[128 * 64];
  __shared__ unsigned short Bs[128 * 64];
  const int tid = (int)threadIdx.x;
  const int lane = tid & 63, wv = tid >> 6;
  const int wm = wv >> 1, wn = wv & 1;
  const int tcol = lane & 15, quad = lane >> 4;
  f32x4 acc[4][4] = {};
  for (int kc = k0; kc < k1; ++kc) {
    __syncthreads();
    stage_tile(W + (size_t)t0 * T_ + kc * 64, T_, As, tid);    // A[m=t][k=s]
    stage_tile(hbT + (size_t)d0 * T_ + kc * 64, T_, Bs, tid);  // B[n=d][k=s]
    __syncthreads();
    #pragma unroll
    for (int kk = 0; kk < 2; ++kk) {
      u16x8 af[4], bf[4];
      #pragma unroll
      for (int mi = 0; mi < 4; ++mi)
        af[mi] = ld16(&As[(wm * 64 + mi * 16 + tcol) * 64 + kk * 32 + quad * 8]);
      #pragma unroll
      for (int ni = 0; ni < 4; ++ni)
        bf[ni] = ld16(&Bs[(wn * 64 + ni * 16 + tcol) * 64 + kk * 32 + quad * 8]);
      #pragma unroll
      for (int mi = 0; mi < 4; ++mi)
        #pragma unroll
        for (int ni = 0; ni < 4; ++ni)
          acc[mi][ni] = mfma16(af[mi], bf[ni], acc[mi][ni]);
    }
  }
  // C-layout: row = t offset, col = d offset; gacc is t-major so the 4 regs of
  // each f32x4 hit 4 different rows; the 16 tcol lanes are contiguous in d.
  #pragma unroll
  for (int mi = 0; mi < 4; ++mi) {
    #pragma unroll
    for (int ni = 0; ni < 4; ++ni) {
      const int t = t0 + wm * 64 + mi * 16 + quad * 4;
      const int d = d0 + wn * 64 + ni * 16 + tcol;
      float* gp = gacc + (size_t)t * D_ + d;
      atomicAdd(gp, acc[mi][ni][0]);
      atomicAdd(gp + D_, acc[mi][ni][1]);
      atomicAdd(gp + 2 * D_, acc[mi][ni][2]);
      atomicAdd(gp + 3 * D_, acc[mi][ni][3]);
    }
  }
}

// ---------- gfin: g = gacc/L; gb = bf16(g); gn2; dist2 ----------
__global__ __launch_bounds__(256) void k_gfin(const float* __restrict__ gacc,
    const float* __restrict__ L, const float* __restrict__ x,
    const float* __restrict__ invnorm, unsigned short* __restrict__ gb,
    float* __restrict__ gn2, float* __restrict__ dist2) {
  const int t = (int)blockIdx.x, tid = (int)threadIdx.x;
  const float invL = 1.0f / L[t];
  const float inr = invnorm[t];
  float sg = 0.f, sd = 0.f;
  const int c = tid * 4;
  if (c < D_) {
    float4 gv = *(const float4*)(gacc + (size_t)t * D_ + c);
    gv.x *= invL; gv.y *= invL; gv.z *= invL; gv.w *= invL;
    *(ushort4*)(gb + (size_t)t * D_ + c) =
        make_ushort4(f2bf(gv.x), f2bf(gv.y), f2bf(gv.z), f2bf(gv.w));
    const float4 hv = *(const float4*)(x + (size_t)t * D_ + c);
    const float e0 = hv.x * inr - gv.x, e1 = hv.y * inr - gv.y;
    const float e2 = hv.z * inr - gv.z, e3 = hv.w * inr - gv.w;
    sg = gv.x * gv.x + gv.y * gv.y + gv.z * gv.z + gv.w * gv.w;
    sd = e0 * e0 + e1 * e1 + e2 * e2 + e3 * e3;
  }
  __shared__ float sb1[4], sb2[4];
  #pragma unroll
  for (int off = 32; off > 0; off >>= 1) {
    sg += __shfl_down(sg, off, 64);
    sd += __shfl_down(sd, off, 64);
  }
  if ((tid & 63) == 0) { sb1[tid >> 6] = sg; sb2[tid >> 6] = sd; }
  __syncthreads();
  if (tid == 0) {
    gn2[t]   = sb1[0] + sb1[1] + sb1[2] + sb1[3];
    dist2[t] = sb2[0] + sb2[1] + sb2[2] + sb2[3];
  }
}

// ---------- GEMM3: cross = g h^T (528 causal tiles); causal row-max of d2 ----------
__global__ __launch_bounds__(256) void k_gemm3(const unsigned short* __restrict__ gb,
    const unsigned short* __restrict__ hb, const float* __restrict__ gn2,
    unsigned int* __restrict__ dmaxu) {
  int ti, sj;
  tri_decode((int)blockIdx.x, ti, sj);
  const int t0 = ti * 128, s0 = sj * 128;
  __shared__ unsigned short As[128 * 64];
  __shared__ unsigned short Bs[128 * 64];
  const int tid = (int)threadIdx.x;
  const int lane = tid & 63, wv = tid >> 6;
  const int wm = wv >> 1, wn = wv & 1;
  const int tcol = lane & 15, quad = lane >> 4;
  f32x4 acc[4][4] = {};
  for (int kc = 0; kc < 14; ++kc) {
    __syncthreads();
    stage_tile(gb + (size_t)t0 * D_ + kc * 64, D_, As, tid);
    stage_tile(hb + (size_t)s0 * D_ + kc * 64, D_, Bs, tid);
    __syncthreads();
    #pragma unroll
    for (int kk = 0; kk < 2; ++kk) {
      u16x8 af[4], bf[4];
      #pragma unroll
      for (int mi = 0; mi < 4; ++mi)
        af[mi] = ld16(&As[(wm * 64 + mi * 16 + tcol) * 64 + kk * 32 + quad * 8]);
      #pragma unroll
      for (int ni = 0; ni < 4; ++ni)
        bf[ni] = ld16(&Bs[(wn * 64 + ni * 16 + tcol) * 64 + kk * 32 + quad * 8]);
      #pragma unroll
      for (int mi = 0; mi < 4; ++mi)
        #pragma unroll
        for (int ni = 0; ni < 4; ++ni)
          acc[mi][ni] = mfma16(af[mi], bf[ni], acc[mi][ni]);
    }
  }
  #pragma unroll
  for (int mi = 0; mi < 4; ++mi) {
    #pragma unroll
    for (int r = 0; r < 4; ++r) {
      const int t = t0 + wm * 64 + mi * 16 + quad * 4 + r;
      const float gn = gn2[t];
      float m2 = 0.f;
      #pragma unroll
      for (int ni = 0; ni < 4; ++ni) {
        const int s = s0 + wn * 64 + ni * 16 + tcol;
        if (t - s >= 0)
          m2 = fmaxf(m2, fmaxf(1.0f - 2.0f * acc[mi][ni][r] + gn, 1e-24f));
      }
      m2 = fmaxf(m2, __shfl_xor(m2, 1, 64));
      m2 = fmaxf(m2, __shfl_xor(m2, 2, 64));
      m2 = fmaxf(m2, __shfl_xor(m2, 4, 64));
      m2 = fmaxf(m2, __shfl_xor(m2, 8, 64));
      if (tcol == 0) atomicMax(&dmaxu[t], __float_as_uint(m2));
    }
  }
}

__global__ __launch_bounds__(256) void k_final(const float* __restrict__ m_t,
    const float* __restrict__ c_t, const float* __restrict__ d_t,
    const float* __restrict__ mu, const float* __restrict__ dist2,
    const unsigned int* __restrict__ dmaxu, float* __restrict__ out) {
  const int t = (int)blockIdx.x * 256 + (int)threadIdx.x;
  if (t >= T_) return;
  float ratio;
  if (t == 0) {
    ratio = 0.f;  // ref: dist~1e-12, dist_max<1e-6 -> 1.0 => ratio ~0
  } else {
    float dmax = sqrtf(__uint_as_float(dmaxu[t]));
    if (dmax < 1e-6f) dmax = 1.0f;
    ratio = sqrtf(fmaxf(dist2[t], 1e-24f)) / (dmax + 1e-8f);
  }
  const float stab = 1.0f - 0.3f * c_t[t] + 0.2f * d_t[t];
  const float xi = 1.0f - mu[0] * m_t[t];
  out[t] = fminf(fmaxf(ratio * stab * xi, 0.f), 1.f);
}

extern "C" void kernel_launch(void* const* d_in, const int* in_sizes, int n_in,
                              void* d_out, int out_size, void* d_ws, size_t ws_size,
                              hipStream_t stream) {
  const float* x   = (const float*)d_in[0];
  const float* m_t = (const float*)d_in[1];
  const float* c_t = (const float*)d_in[2];
  const float* d_t = (const float*)d_in[3];
  const float* mu  = (const float*)d_in[4];
  float* out = (float*)d_out;

  float* ws = (float*)d_ws;
  float* invnorm = ws;                                         // [T]
  float* L       = ws + T_;                                    // [T]
  unsigned int* dmaxu = (unsigned int*)(ws + 2 * (size_t)T_);  // [T]
  float* gn2     = ws + 3 * (size_t)T_;                        // [T]
  float* dist2   = ws + 4 * (size_t)T_;                        // [T]
  float* gacc    = ws + 5 * (size_t)T_;                        // [T*D] fp32
  unsigned short* hb  = (unsigned short*)(gacc + (size_t)T_ * D_);
  unsigned short* hbT = hb + (size_t)T_ * D_;
  unsigned short* gb  = hbT + (size_t)T_ * D_;
  unsigned short* W   = gb + (size_t)T_ * D_;                  // [T*T] bf16

  hipMemsetAsync(L, 0, 2 * (size_t)T_ * sizeof(float), stream);      // L + dmaxu
  hipMemsetAsync(gacc, 0, (size_t)T_ * D_ * sizeof(float), stream);  // split-K acc

  k_prep<<<T_, 256, 0, stream>>>(x, invnorm, hb);
  k_transp<<<dim3(T_ / 32, D_ / 32), 256, 0, stream>>>(hb, hbT);
  k_gemm1<<<528, 256, 0, stream>>>(hb, W, L);
  k_gemm2<<<dim3(32, 7, 8), 256, 0, stream>>>(W, hbT, gacc);
  k_gfin<<<T_, 256, 0, stream>>>(gacc, L, x, invnorm, gb, gn2, dist2);
  k_gemm3<<<528, 256, 0, stream>>>(gb, hb, gn2, dmaxu);
  k_final<<<(T_ + 255) / 256, 256, 0, stream>>>(m_t, c_t, d_t, mu, dist2, dmaxu, out);
}

// Round 5
// 232.018 us; speedup vs baseline: 10.6016x; 1.1747x over previous
//
#include <hip/hip_runtime.h>
#include <math.h>

// SemanticDriftCoeff — bf16 MFMA GEMMs, double-buffered single-barrier K-loop,
// XOR-swizzled LDS (conflict-free b128 frag reads), atomic-free split-K gemm2.
// ws: floats [0,T) invnorm, [T,2T) L, [2T,3T) dmaxu, [3T,4T) gn2, [4T,5T) dist2,
// [5T, 5T+4*T*D) gpart fp32 (4 K-slices); then ushort hb[T*D], hbT[D*T],
// gb[T*D], W[T*T]. ~114 MB.

#define T_ 4096
#define D_ 896

typedef float f32x4 __attribute__((ext_vector_type(4)));
typedef unsigned short u16x8 __attribute__((ext_vector_type(8)));
typedef __bf16 bf16x8 __attribute__((ext_vector_type(8)));

union V16 { uint4 u; u16x8 v; };

__device__ __forceinline__ u16x8 ld16(const unsigned short* p) {
  V16 x; x.u = *(const uint4*)p; return x.v;
}
__device__ __forceinline__ unsigned short f2bf(float f) {  // RNE float->bf16 bits
  unsigned int u = __float_as_uint(f);
  u += 0x7FFFu + ((u >> 16) & 1u);
  return (unsigned short)(u >> 16);
}
__device__ __forceinline__ float bf2f(unsigned short b) {
  return __uint_as_float(((unsigned int)b) << 16);
}
__device__ __forceinline__ f32x4 mfma16(u16x8 a, u16x8 b, f32x4 c) {
  return __builtin_amdgcn_mfma_f32_16x16x32_bf16(
      __builtin_bit_cast(bf16x8, a), __builtin_bit_cast(bf16x8, b), c, 0, 0, 0);
}

typedef __attribute__((address_space(1))) const void glob_cv;
typedef __attribute__((address_space(3))) void lds_v;
__device__ __forceinline__ void gload16(const void* g, void* l) {
  __builtin_amdgcn_global_load_lds((glob_cv*)g, (lds_v*)l, 16, 0, 0);
}

// Stage a 128x64 tile with XOR column-group swizzle: logical 16B-group g of row r
// is stored at physical group g^(r&7). LDS dst stays contiguous in lane order
// (global_load_lds constraint); the permutation is applied to the GLOBAL address.
__device__ __forceinline__ void stage_sw(const unsigned short* __restrict__ g0,
                                         int stride, unsigned short* lds0, int tid) {
  #pragma unroll
  for (int it = 0; it < 4; ++it) {
    const int e = it * 256 + tid;        // 16B unit index 0..1023
    const int row = e >> 3, pg = e & 7;
    const int gg = pg ^ (row & 7);       // logical group fetched into physical slot
    gload16(g0 + (size_t)row * stride + gg * 8, lds0 + e * 8);
  }
}

// One 64-deep K-chunk of 128x128 MFMA work from swizzled LDS tiles.
__device__ __forceinline__ void mfma_chunk(const unsigned short* As,
    const unsigned short* Bs, int wm, int wn, int tcol, int quad, f32x4 acc[4][4]) {
  const int sx = tcol & 7;               // row&7 == tcol&7 for all frag rows
  #pragma unroll
  for (int kk = 0; kk < 2; ++kk) {
    u16x8 af[4], bf[4];
    const int go = ((kk * 4 + quad) ^ sx) * 8;
    #pragma unroll
    for (int mi = 0; mi < 4; ++mi)
      af[mi] = ld16(&As[(wm * 64 + mi * 16 + tcol) * 64 + go]);
    #pragma unroll
    for (int ni = 0; ni < 4; ++ni)
      bf[ni] = ld16(&Bs[(wn * 64 + ni * 16 + tcol) * 64 + go]);
    #pragma unroll
    for (int mi = 0; mi < 4; ++mi)
      #pragma unroll
      for (int ni = 0; ni < 4; ++ni)
        acc[mi][ni] = mfma16(af[mi], bf[ni], acc[mi][ni]);
  }
}

// triangular decode: b -> (ti, sj), sj <= ti
__device__ __forceinline__ void tri_decode(int b, int& ti, int& sj) {
  ti = (int)((sqrtf(8.0f * (float)b + 1.0f) - 1.0f) * 0.5f);
  while ((ti + 1) * (ti + 2) / 2 <= b) ++ti;
  while (ti * (ti + 1) / 2 > b) --ti;
  sj = b - ti * (ti + 1) / 2;
}

// ---------- prep: invnorm + bf16 normalized rows ----------
__global__ __launch_bounds__(256) void k_prep(const float* __restrict__ x,
    float* __restrict__ invnorm, unsigned short* __restrict__ hb) {
  const int t = (int)blockIdx.x, tid = (int)threadIdx.x;
  const int c = tid * 4;
  float4 v = make_float4(0.f, 0.f, 0.f, 0.f);
  float s = 0.f;
  if (c < D_) {
    v = *(const float4*)(x + (size_t)t * D_ + c);
    s = v.x * v.x + v.y * v.y + v.z * v.z + v.w * v.w;
  }
  __shared__ float sb[4];
  __shared__ float sinv;
  #pragma unroll
  for (int off = 32; off > 0; off >>= 1) s += __shfl_down(s, off, 64);
  if ((tid & 63) == 0) sb[tid >> 6] = s;
  __syncthreads();
  if (tid == 0) {
    const float tot = sb[0] + sb[1] + sb[2] + sb[3];
    const float iv = 1.0f / fmaxf(sqrtf(tot), 1e-12f);
    invnorm[t] = iv; sinv = iv;
  }
  __syncthreads();
  if (c < D_) {
    const float iv = sinv;
    *(ushort4*)(hb + (size_t)t * D_ + c) = make_ushort4(
        f2bf(v.x * iv), f2bf(v.y * iv), f2bf(v.z * iv), f2bf(v.w * iv));
  }
}

// ---------- 32x32 bf16 transpose hb -> hbT ----------
__global__ __launch_bounds__(256) void k_transp(const unsigned short* __restrict__ hb,
                                                unsigned short* __restrict__ hbT) {
  __shared__ unsigned short Ts[32][36];
  const int t0 = (int)blockIdx.x * 32, d0 = (int)blockIdx.y * 32;
  const int r = (int)threadIdx.x >> 3, c = ((int)threadIdx.x & 7) * 4;
  const ushort4 v = *(const ushort4*)(hb + (size_t)(t0 + r) * D_ + d0 + c);
  Ts[r][c] = v.x; Ts[r][c + 1] = v.y; Ts[r][c + 2] = v.z; Ts[r][c + 3] = v.w;
  __syncthreads();
  const ushort4 o = make_ushort4(Ts[c][r], Ts[c + 1][r], Ts[c + 2][r], Ts[c + 3][r]);
  *(ushort4*)(hbT + (size_t)(d0 + r) * T_ + t0 + c) = o;
}

// ---------- GEMM1: S = h h^T (528 causal tiles); epilogue W = exp, L = rowsum ----------
__global__ __launch_bounds__(256) void k_gemm1(const unsigned short* __restrict__ hb,
    unsigned short* __restrict__ W, float* __restrict__ L) {
  int ti, sj;
  tri_decode((int)blockIdx.x, ti, sj);
  const int t0 = ti * 128, s0 = sj * 128;
  __shared__ unsigned short As[2][128 * 64];
  __shared__ unsigned short Bs[2][128 * 64];
  const int tid = (int)threadIdx.x;
  const int lane = tid & 63, wv = tid >> 6;
  const int wm = wv >> 1, wn = wv & 1;
  const int tcol = lane & 15, quad = lane >> 4;
  f32x4 acc[4][4] = {};
  stage_sw(hb + (size_t)t0 * D_, D_, As[0], tid);
  stage_sw(hb + (size_t)s0 * D_, D_, Bs[0], tid);
  for (int kc = 0; kc < 14; ++kc) {
    __syncthreads();   // drains vmcnt -> buf[kc&1] ready; readers done with other buf
    if (kc < 13) {
      stage_sw(hb + (size_t)t0 * D_ + (kc + 1) * 64, D_, As[(kc + 1) & 1], tid);
      stage_sw(hb + (size_t)s0 * D_ + (kc + 1) * 64, D_, Bs[(kc + 1) & 1], tid);
    }
    mfma_chunk(As[kc & 1], Bs[kc & 1], wm, wn, tcol, quad, acc);
  }
  #pragma unroll
  for (int mi = 0; mi < 4; ++mi) {
    #pragma unroll
    for (int r = 0; r < 4; ++r) {
      const int t = t0 + wm * 64 + mi * 16 + quad * 4 + r;
      float lsum = 0.f;
      #pragma unroll
      for (int ni = 0; ni < 4; ++ni) {
        const int s = s0 + wn * 64 + ni * 16 + tcol;
        const int dt = t - s;
        float wval = 0.f;
        if (dt >= 0)
          wval = __expf(acc[mi][ni][r] * (__expf(-0.1f * (float)dt) * 0.033407657f));
        const unsigned short wb = f2bf(wval);
        W[(size_t)t * T_ + s] = wb;
        lsum += bf2f(wb);
      }
      lsum += __shfl_xor(lsum, 1, 64);
      lsum += __shfl_xor(lsum, 2, 64);
      lsum += __shfl_xor(lsum, 4, 64);
      lsum += __shfl_xor(lsum, 8, 64);
      if (tcol == 0) atomicAdd(&L[t], lsum);
    }
  }
}

// ---------- GEMM2 (split-K=4, atomic-free): gpart[z][t][d] = sum_s W[t][s] hbT[d][s] ----------
__global__ __launch_bounds__(256) void k_gemm2(const unsigned short* __restrict__ W,
    const unsigned short* __restrict__ hbT, float* __restrict__ gpart) {
  const int tj = (int)blockIdx.x, dj = (int)blockIdx.y, z = (int)blockIdx.z;
  const int nk = 2 * (tj + 1);          // causal chunks: s < t0+128
  const int k0 = z * 16;
  if (k0 >= nk) return;
  const int k1 = min(k0 + 16, nk);
  const int t0 = tj * 128, d0 = dj * 128;
  __shared__ unsigned short As[2][128 * 64];
  __shared__ unsigned short Bs[2][128 * 64];
  const int tid = (int)threadIdx.x;
  const int lane = tid & 63, wv = tid >> 6;
  const int wm = wv >> 1, wn = wv & 1;
  const int tcol = lane & 15, quad = lane >> 4;
  f32x4 acc[4][4] = {};
  stage_sw(W + (size_t)t0 * T_ + k0 * 64, T_, As[k0 & 1], tid);
  stage_sw(hbT + (size_t)d0 * T_ + k0 * 64, T_, Bs[k0 & 1], tid);
  for (int kc = k0; kc < k1; ++kc) {
    __syncthreads();
    if (kc + 1 < k1) {
      stage_sw(W + (size_t)t0 * T_ + (kc + 1) * 64, T_, As[(kc + 1) & 1], tid);
      stage_sw(hbT + (size_t)d0 * T_ + (kc + 1) * 64, T_, Bs[(kc + 1) & 1], tid);
    }
    mfma_chunk(As[kc & 1], Bs[kc & 1], wm, wn, tcol, quad, acc);
  }
  float* base = gpart + (size_t)z * T_ * D_;
  #pragma unroll
  for (int mi = 0; mi < 4; ++mi) {
    #pragma unroll
    for (int ni = 0; ni < 4; ++ni) {
      const int t = t0 + wm * 64 + mi * 16 + quad * 4;
      const int d = d0 + wn * 64 + ni * 16 + tcol;
      float* gp = base + (size_t)t * D_ + d;
      gp[0]        = acc[mi][ni][0];
      gp[D_]       = acc[mi][ni][1];
      gp[2 * D_]   = acc[mi][ni][2];
      gp[3 * D_]   = acc[mi][ni][3];
    }
  }
}

// ---------- gfin: g = (sum_z gpart)/L; gb = bf16(g); gn2; dist2 ----------
__global__ __launch_bounds__(256) void k_gfin(const float* __restrict__ gpart,
    const float* __restrict__ L, const float* __restrict__ x,
    const float* __restrict__ invnorm, unsigned short* __restrict__ gb,
    float* __restrict__ gn2, float* __restrict__ dist2) {
  const int t = (int)blockIdx.x, tid = (int)threadIdx.x;
  const int tj = t >> 7;
  const int nz = (tj + 8) >> 3;          // ceil((tj+1)/8) valid K-slices
  const float invL = 1.0f / L[t];
  const float inr = invnorm[t];
  float sg = 0.f, sd = 0.f;
  const int c = tid * 4;
  if (c < D_) {
    float4 gv = make_float4(0.f, 0.f, 0.f, 0.f);
    for (int z = 0; z < nz; ++z) {
      const float4 p = *(const float4*)(gpart + (size_t)z * T_ * D_ + (size_t)t * D_ + c);
      gv.x += p.x; gv.y += p.y; gv.z += p.z; gv.w += p.w;
    }
    gv.x *= invL; gv.y *= invL; gv.z *= invL; gv.w *= invL;
    *(ushort4*)(gb + (size_t)t * D_ + c) =
        make_ushort4(f2bf(gv.x), f2bf(gv.y), f2bf(gv.z), f2bf(gv.w));
    const float4 hv = *(const float4*)(x + (size_t)t * D_ + c);
    const float e0 = hv.x * inr - gv.x, e1 = hv.y * inr - gv.y;
    const float e2 = hv.z * inr - gv.z, e3 = hv.w * inr - gv.w;
    sg = gv.x * gv.x + gv.y * gv.y + gv.z * gv.z + gv.w * gv.w;
    sd = e0 * e0 + e1 * e1 + e2 * e2 + e3 * e3;
  }
  __shared__ float sb1[4], sb2[4];
  #pragma unroll
  for (int off = 32; off > 0; off >>= 1) {
    sg += __shfl_down(sg, off, 64);
    sd += __shfl_down(sd, off, 64);
  }
  if ((tid & 63) == 0) { sb1[tid >> 6] = sg; sb2[tid >> 6] = sd; }
  __syncthreads();
  if (tid == 0) {
    gn2[t]   = sb1[0] + sb1[1] + sb1[2] + sb1[3];
    dist2[t] = sb2[0] + sb2[1] + sb2[2] + sb2[3];
  }
}

// ---------- GEMM3: cross = g h^T (528 causal tiles); causal row-max of d2 ----------
__global__ __launch_bounds__(256) void k_gemm3(const unsigned short* __restrict__ gb,
    const unsigned short* __restrict__ hb, const float* __restrict__ gn2,
    unsigned int* __restrict__ dmaxu) {
  int ti, sj;
  tri_decode((int)blockIdx.x, ti, sj);
  const int t0 = ti * 128, s0 = sj * 128;
  __shared__ unsigned short As[2][128 * 64];
  __shared__ unsigned short Bs[2][128 * 64];
  const int tid = (int)threadIdx.x;
  const int lane = tid & 63, wv = tid >> 6;
  const int wm = wv >> 1, wn = wv & 1;
  const int tcol = lane & 15, quad = lane >> 4;
  f32x4 acc[4][4] = {};
  stage_sw(gb + (size_t)t0 * D_, D_, As[0], tid);
  stage_sw(hb + (size_t)s0 * D_, D_, Bs[0], tid);
  for (int kc = 0; kc < 14; ++kc) {
    __syncthreads();
    if (kc < 13) {
      stage_sw(gb + (size_t)t0 * D_ + (kc + 1) * 64, D_, As[(kc + 1) & 1], tid);
      stage_sw(hb + (size_t)s0 * D_ + (kc + 1) * 64, D_, Bs[(kc + 1) & 1], tid);
    }
    mfma_chunk(As[kc & 1], Bs[kc & 1], wm, wn, tcol, quad, acc);
  }
  #pragma unroll
  for (int mi = 0; mi < 4; ++mi) {
    #pragma unroll
    for (int r = 0; r < 4; ++r) {
      const int t = t0 + wm * 64 + mi * 16 + quad * 4 + r;
      const float gn = gn2[t];
      float m2 = 0.f;
      #pragma unroll
      for (int ni = 0; ni < 4; ++ni) {
        const int s = s0 + wn * 64 + ni * 16 + tcol;
        if (t - s >= 0)
          m2 = fmaxf(m2, fmaxf(1.0f - 2.0f * acc[mi][ni][r] + gn, 1e-24f));
      }
      m2 = fmaxf(m2, __shfl_xor(m2, 1, 64));
      m2 = fmaxf(m2, __shfl_xor(m2, 2, 64));
      m2 = fmaxf(m2, __shfl_xor(m2, 4, 64));
      m2 = fmaxf(m2, __shfl_xor(m2, 8, 64));
      if (tcol == 0) atomicMax(&dmaxu[t], __float_as_uint(m2));
    }
  }
}

__global__ __launch_bounds__(256) void k_final(const float* __restrict__ m_t,
    const float* __restrict__ c_t, const float* __restrict__ d_t,
    const float* __restrict__ mu, const float* __restrict__ dist2,
    const unsigned int* __restrict__ dmaxu, float* __restrict__ out) {
  const int t = (int)blockIdx.x * 256 + (int)threadIdx.x;
  if (t >= T_) return;
  float ratio;
  if (t == 0) {
    ratio = 0.f;  // ref: dist~1e-12, dist_max<1e-6 -> 1.0 => ratio ~0
  } else {
    float dmax = sqrtf(__uint_as_float(dmaxu[t]));
    if (dmax < 1e-6f) dmax = 1.0f;
    ratio = sqrtf(fmaxf(dist2[t], 1e-24f)) / (dmax + 1e-8f);
  }
  const float stab = 1.0f - 0.3f * c_t[t] + 0.2f * d_t[t];
  const float xi = 1.0f - mu[0] * m_t[t];
  out[t] = fminf(fmaxf(ratio * stab * xi, 0.f), 1.f);
}

extern "C" void kernel_launch(void* const* d_in, const int* in_sizes, int n_in,
                              void* d_out, int out_size, void* d_ws, size_t ws_size,
                              hipStream_t stream) {
  const float* x   = (const float*)d_in[0];
  const float* m_t = (const float*)d_in[1];
  const float* c_t = (const float*)d_in[2];
  const float* d_t = (const float*)d_in[3];
  const float* mu  = (const float*)d_in[4];
  float* out = (float*)d_out;

  float* ws = (float*)d_ws;
  float* invnorm = ws;                                         // [T]
  float* L       = ws + T_;                                    // [T]
  unsigned int* dmaxu = (unsigned int*)(ws + 2 * (size_t)T_);  // [T]
  float* gn2     = ws + 3 * (size_t)T_;                        // [T]
  float* dist2   = ws + 4 * (size_t)T_;                        // [T]
  float* gpart   = ws + 5 * (size_t)T_;                        // [4][T*D] fp32
  unsigned short* hb  = (unsigned short*)(gpart + 4 * (size_t)T_ * D_);
  unsigned short* hbT = hb + (size_t)T_ * D_;
  unsigned short* gb  = hbT + (size_t)T_ * D_;
  unsigned short* W   = gb + (size_t)T_ * D_;                  // [T*T] bf16

  hipMemsetAsync(L, 0, 2 * (size_t)T_ * sizeof(float), stream);  // L + dmaxu only

  k_prep<<<T_, 256, 0, stream>>>(x, invnorm, hb);
  k_transp<<<dim3(T_ / 32, D_ / 32), 256, 0, stream>>>(hb, hbT);
  k_gemm1<<<528, 256, 0, stream>>>(hb, W, L);
  k_gemm2<<<dim3(32, 7, 4), 256, 0, stream>>>(W, hbT, gpart);
  k_gfin<<<T_, 256, 0, stream>>>(gpart, L, x, invnorm, gb, gn2, dist2);
  k_gemm3<<<528, 256, 0, stream>>>(gb, hb, gn2, dmaxu);
  k_final<<<(T_ + 255) / 256, 256, 0, stream>>>(m_t, c_t, d_t, mu, dist2, dmaxu, out);
}

// Round 6
// 229.880 us; speedup vs baseline: 10.7002x; 1.0093x over previous
//
#include <hip/hip_runtime.h>
#include <math.h>

// SemanticDriftCoeff — bf16 MFMA GEMMs, single-buffered m97-style chunk loop
// (32 KB LDS -> 5 blocks/CU), XOR-swizzled LDS (0 bank conflicts),
// atomic-free split-K gemm2.
// ws: floats [0,T) invnorm, [T,2T) L, [2T,3T) dmaxu, [3T,4T) gn2, [4T,5T) dist2,
// [5T, 5T+4*T*D) gpart fp32 (4 K-slices); then ushort hb[T*D], hbT[D*T],
// gb[T*D], W[T*T]. ~114 MB.

#define T_ 4096
#define D_ 896

typedef float f32x4 __attribute__((ext_vector_type(4)));
typedef unsigned short u16x8 __attribute__((ext_vector_type(8)));
typedef __bf16 bf16x8 __attribute__((ext_vector_type(8)));

union V16 { uint4 u; u16x8 v; };

__device__ __forceinline__ u16x8 ld16(const unsigned short* p) {
  V16 x; x.u = *(const uint4*)p; return x.v;
}
__device__ __forceinline__ unsigned short f2bf(float f) {  // RNE float->bf16 bits
  unsigned int u = __float_as_uint(f);
  u += 0x7FFFu + ((u >> 16) & 1u);
  return (unsigned short)(u >> 16);
}
__device__ __forceinline__ float bf2f(unsigned short b) {
  return __uint_as_float(((unsigned int)b) << 16);
}
__device__ __forceinline__ f32x4 mfma16(u16x8 a, u16x8 b, f32x4 c) {
  return __builtin_amdgcn_mfma_f32_16x16x32_bf16(
      __builtin_bit_cast(bf16x8, a), __builtin_bit_cast(bf16x8, b), c, 0, 0, 0);
}

typedef __attribute__((address_space(1))) const void glob_cv;
typedef __attribute__((address_space(3))) void lds_v;
__device__ __forceinline__ void gload16(const void* g, void* l) {
  __builtin_amdgcn_global_load_lds((glob_cv*)g, (lds_v*)l, 16, 0, 0);
}

// Stage a 128x64 tile with XOR column-group swizzle: logical 16B-group g of row r
// is stored at physical group g^(r&7). LDS dst stays contiguous in lane order
// (global_load_lds constraint); the permutation is applied to the GLOBAL address.
__device__ __forceinline__ void stage_sw(const unsigned short* __restrict__ g0,
                                         int stride, unsigned short* lds0, int tid) {
  #pragma unroll
  for (int it = 0; it < 4; ++it) {
    const int e = it * 256 + tid;        // 16B unit index 0..1023
    const int row = e >> 3, pg = e & 7;
    const int gg = pg ^ (row & 7);       // logical group fetched into physical slot
    gload16(g0 + (size_t)row * stride + gg * 8, lds0 + e * 8);
  }
}

// One 64-deep K-chunk of 128x128 MFMA work from swizzled LDS tiles.
__device__ __forceinline__ void mfma_chunk(const unsigned short* As,
    const unsigned short* Bs, int wm, int wn, int tcol, int quad, f32x4 acc[4][4]) {
  const int sx = tcol & 7;               // row&7 == tcol&7 for all frag rows
  #pragma unroll
  for (int kk = 0; kk < 2; ++kk) {
    u16x8 af[4], bf[4];
    const int go = ((kk * 4 + quad) ^ sx) * 8;
    #pragma unroll
    for (int mi = 0; mi < 4; ++mi)
      af[mi] = ld16(&As[(wm * 64 + mi * 16 + tcol) * 64 + go]);
    #pragma unroll
    for (int ni = 0; ni < 4; ++ni)
      bf[ni] = ld16(&Bs[(wn * 64 + ni * 16 + tcol) * 64 + go]);
    #pragma unroll
    for (int mi = 0; mi < 4; ++mi)
      #pragma unroll
      for (int ni = 0; ni < 4; ++ni)
        acc[mi][ni] = mfma16(af[mi], bf[ni], acc[mi][ni]);
  }
}

// triangular decode: b -> (ti, sj), sj <= ti
__device__ __forceinline__ void tri_decode(int b, int& ti, int& sj) {
  ti = (int)((sqrtf(8.0f * (float)b + 1.0f) - 1.0f) * 0.5f);
  while ((ti + 1) * (ti + 2) / 2 <= b) ++ti;
  while (ti * (ti + 1) / 2 > b) --ti;
  sj = b - ti * (ti + 1) / 2;
}

// ---------- prep: invnorm + bf16 normalized rows ----------
__global__ __launch_bounds__(256) void k_prep(const float* __restrict__ x,
    float* __restrict__ invnorm, unsigned short* __restrict__ hb) {
  const int t = (int)blockIdx.x, tid = (int)threadIdx.x;
  const int c = tid * 4;
  float4 v = make_float4(0.f, 0.f, 0.f, 0.f);
  float s = 0.f;
  if (c < D_) {
    v = *(const float4*)(x + (size_t)t * D_ + c);
    s = v.x * v.x + v.y * v.y + v.z * v.z + v.w * v.w;
  }
  __shared__ float sb[4];
  __shared__ float sinv;
  #pragma unroll
  for (int off = 32; off > 0; off >>= 1) s += __shfl_down(s, off, 64);
  if ((tid & 63) == 0) sb[tid >> 6] = s;
  __syncthreads();
  if (tid == 0) {
    const float tot = sb[0] + sb[1] + sb[2] + sb[3];
    const float iv = 1.0f / fmaxf(sqrtf(tot), 1e-12f);
    invnorm[t] = iv; sinv = iv;
  }
  __syncthreads();
  if (c < D_) {
    const float iv = sinv;
    *(ushort4*)(hb + (size_t)t * D_ + c) = make_ushort4(
        f2bf(v.x * iv), f2bf(v.y * iv), f2bf(v.z * iv), f2bf(v.w * iv));
  }
}

// ---------- 32x32 bf16 transpose hb -> hbT ----------
__global__ __launch_bounds__(256) void k_transp(const unsigned short* __restrict__ hb,
                                                unsigned short* __restrict__ hbT) {
  __shared__ unsigned short Ts[32][36];
  const int t0 = (int)blockIdx.x * 32, d0 = (int)blockIdx.y * 32;
  const int r = (int)threadIdx.x >> 3, c = ((int)threadIdx.x & 7) * 4;
  const ushort4 v = *(const ushort4*)(hb + (size_t)(t0 + r) * D_ + d0 + c);
  Ts[r][c] = v.x; Ts[r][c + 1] = v.y; Ts[r][c + 2] = v.z; Ts[r][c + 3] = v.w;
  __syncthreads();
  const ushort4 o = make_ushort4(Ts[c][r], Ts[c + 1][r], Ts[c + 2][r], Ts[c + 3][r]);
  *(ushort4*)(hbT + (size_t)(d0 + r) * T_ + t0 + c) = o;
}

// ---------- GEMM1: S = h h^T (528 causal tiles); epilogue W = exp, L = rowsum ----------
__global__ __launch_bounds__(256, 5) void k_gemm1(const unsigned short* __restrict__ hb,
    unsigned short* __restrict__ W, float* __restrict__ L) {
  int ti, sj;
  tri_decode((int)blockIdx.x, ti, sj);
  const int t0 = ti * 128, s0 = sj * 128;
  __shared__ unsigned short As[128 * 64];
  __shared__ unsigned short Bs[128 * 64];
  const int tid = (int)threadIdx.x;
  const int lane = tid & 63, wv = tid >> 6;
  const int wm = wv >> 1, wn = wv & 1;
  const int tcol = lane & 15, quad = lane >> 4;
  f32x4 acc[4][4] = {};
  for (int kc = 0; kc < 14; ++kc) {
    __syncthreads();   // readers done with buffer
    stage_sw(hb + (size_t)t0 * D_ + kc * 64, D_, As, tid);
    stage_sw(hb + (size_t)s0 * D_ + kc * 64, D_, Bs, tid);
    __syncthreads();   // vmcnt(0) drained, tiles ready
    mfma_chunk(As, Bs, wm, wn, tcol, quad, acc);
  }
  #pragma unroll
  for (int mi = 0; mi < 4; ++mi) {
    #pragma unroll
    for (int r = 0; r < 4; ++r) {
      const int t = t0 + wm * 64 + mi * 16 + quad * 4 + r;
      float lsum = 0.f;
      #pragma unroll
      for (int ni = 0; ni < 4; ++ni) {
        const int s = s0 + wn * 64 + ni * 16 + tcol;
        const int dt = t - s;
        float wval = 0.f;
        if (dt >= 0)
          wval = __expf(acc[mi][ni][r] * (__expf(-0.1f * (float)dt) * 0.033407657f));
        const unsigned short wb = f2bf(wval);
        W[(size_t)t * T_ + s] = wb;
        lsum += bf2f(wb);
      }
      lsum += __shfl_xor(lsum, 1, 64);
      lsum += __shfl_xor(lsum, 2, 64);
      lsum += __shfl_xor(lsum, 4, 64);
      lsum += __shfl_xor(lsum, 8, 64);
      if (tcol == 0) atomicAdd(&L[t], lsum);
    }
  }
}

// ---------- GEMM2 (split-K=4, atomic-free): gpart[z][t][d] = sum_s W[t][s] hbT[d][s] ----------
__global__ __launch_bounds__(256, 5) void k_gemm2(const unsigned short* __restrict__ W,
    const unsigned short* __restrict__ hbT, float* __restrict__ gpart) {
  const int tj = (int)blockIdx.x, dj = (int)blockIdx.y, z = (int)blockIdx.z;
  const int nk = 2 * (tj + 1);          // causal chunks: s < t0+128
  const int k0 = z * 16;
  if (k0 >= nk) return;
  const int k1 = min(k0 + 16, nk);
  const int t0 = tj * 128, d0 = dj * 128;
  __shared__ unsigned short As[128 * 64];
  __shared__ unsigned short Bs[128 * 64];
  const int tid = (int)threadIdx.x;
  const int lane = tid & 63, wv = tid >> 6;
  const int wm = wv >> 1, wn = wv & 1;
  const int tcol = lane & 15, quad = lane >> 4;
  f32x4 acc[4][4] = {};
  for (int kc = k0; kc < k1; ++kc) {
    __syncthreads();
    stage_sw(W + (size_t)t0 * T_ + kc * 64, T_, As, tid);    // A[m=t][k=s]
    stage_sw(hbT + (size_t)d0 * T_ + kc * 64, T_, Bs, tid);  // B[n=d][k=s]
    __syncthreads();
    mfma_chunk(As, Bs, wm, wn, tcol, quad, acc);
  }
  float* base = gpart + (size_t)z * T_ * D_;
  #pragma unroll
  for (int mi = 0; mi < 4; ++mi) {
    #pragma unroll
    for (int ni = 0; ni < 4; ++ni) {
      const int t = t0 + wm * 64 + mi * 16 + quad * 4;
      const int d = d0 + wn * 64 + ni * 16 + tcol;
      float* gp = base + (size_t)t * D_ + d;
      gp[0]        = acc[mi][ni][0];
      gp[D_]       = acc[mi][ni][1];
      gp[2 * D_]   = acc[mi][ni][2];
      gp[3 * D_]   = acc[mi][ni][3];
    }
  }
}

// ---------- gfin: g = (sum_z gpart)/L; gb = bf16(g); gn2; dist2 ----------
__global__ __launch_bounds__(256) void k_gfin(const float* __restrict__ gpart,
    const float* __restrict__ L, const float* __restrict__ x,
    const float* __restrict__ invnorm, unsigned short* __restrict__ gb,
    float* __restrict__ gn2, float* __restrict__ dist2) {
  const int t = (int)blockIdx.x, tid = (int)threadIdx.x;
  const int tj = t >> 7;
  const int nz = (tj + 8) >> 3;          // ceil((tj+1)/8) valid K-slices
  const float invL = 1.0f / L[t];
  const float inr = invnorm[t];
  float sg = 0.f, sd = 0.f;
  const int c = tid * 4;
  if (c < D_) {
    float4 gv = make_float4(0.f, 0.f, 0.f, 0.f);
    for (int z = 0; z < nz; ++z) {
      const float4 p = *(const float4*)(gpart + (size_t)z * T_ * D_ + (size_t)t * D_ + c);
      gv.x += p.x; gv.y += p.y; gv.z += p.z; gv.w += p.w;
    }
    gv.x *= invL; gv.y *= invL; gv.z *= invL; gv.w *= invL;
    *(ushort4*)(gb + (size_t)t * D_ + c) =
        make_ushort4(f2bf(gv.x), f2bf(gv.y), f2bf(gv.z), f2bf(gv.w));
    const float4 hv = *(const float4*)(x + (size_t)t * D_ + c);
    const float e0 = hv.x * inr - gv.x, e1 = hv.y * inr - gv.y;
    const float e2 = hv.z * inr - gv.z, e3 = hv.w * inr - gv.w;
    sg = gv.x * gv.x + gv.y * gv.y + gv.z * gv.z + gv.w * gv.w;
    sd = e0 * e0 + e1 * e1 + e2 * e2 + e3 * e3;
  }
  __shared__ float sb1[4], sb2[4];
  #pragma unroll
  for (int off = 32; off > 0; off >>= 1) {
    sg += __shfl_down(sg, off, 64);
    sd += __shfl_down(sd, off, 64);
  }
  if ((tid & 63) == 0) { sb1[tid >> 6] = sg; sb2[tid >> 6] = sd; }
  __syncthreads();
  if (tid == 0) {
    gn2[t]   = sb1[0] + sb1[1] + sb1[2] + sb1[3];
    dist2[t] = sb2[0] + sb2[1] + sb2[2] + sb2[3];
  }
}

// ---------- GEMM3: cross = g h^T (528 causal tiles); causal row-max of d2 ----------
__global__ __launch_bounds__(256, 5) void k_gemm3(const unsigned short* __restrict__ gb,
    const unsigned short* __restrict__ hb, const float* __restrict__ gn2,
    unsigned int* __restrict__ dmaxu) {
  int ti, sj;
  tri_decode((int)blockIdx.x, ti, sj);
  const int t0 = ti * 128, s0 = sj * 128;
  __shared__ unsigned short As[128 * 64];
  __shared__ unsigned short Bs[128 * 64];
  const int tid = (int)threadIdx.x;
  const int lane = tid & 63, wv = tid >> 6;
  const int wm = wv >> 1, wn = wv & 1;
  const int tcol = lane & 15, quad = lane >> 4;
  f32x4 acc[4][4] = {};
  for (int kc = 0; kc < 14; ++kc) {
    __syncthreads();
    stage_sw(gb + (size_t)t0 * D_ + kc * 64, D_, As, tid);
    stage_sw(hb + (size_t)s0 * D_ + kc * 64, D_, Bs, tid);
    __syncthreads();
    mfma_chunk(As, Bs, wm, wn, tcol, quad, acc);
  }
  #pragma unroll
  for (int mi = 0; mi < 4; ++mi) {
    #pragma unroll
    for (int r = 0; r < 4; ++r) {
      const int t = t0 + wm * 64 + mi * 16 + quad * 4 + r;
      const float gn = gn2[t];
      float m2 = 0.f;
      #pragma unroll
      for (int ni = 0; ni < 4; ++ni) {
        const int s = s0 + wn * 64 + ni * 16 + tcol;
        if (t - s >= 0)
          m2 = fmaxf(m2, fmaxf(1.0f - 2.0f * acc[mi][ni][r] + gn, 1e-24f));
      }
      m2 = fmaxf(m2, __shfl_xor(m2, 1, 64));
      m2 = fmaxf(m2, __shfl_xor(m2, 2, 64));
      m2 = fmaxf(m2, __shfl_xor(m2, 4, 64));
      m2 = fmaxf(m2, __shfl_xor(m2, 8, 64));
      if (tcol == 0) atomicMax(&dmaxu[t], __float_as_uint(m2));
    }
  }
}

__global__ __launch_bounds__(256) void k_final(const float* __restrict__ m_t,
    const float* __restrict__ c_t, const float* __restrict__ d_t,
    const float* __restrict__ mu, const float* __restrict__ dist2,
    const unsigned int* __restrict__ dmaxu, float* __restrict__ out) {
  const int t = (int)blockIdx.x * 256 + (int)threadIdx.x;
  if (t >= T_) return;
  float ratio;
  if (t == 0) {
    ratio = 0.f;  // ref: dist~1e-12, dist_max<1e-6 -> 1.0 => ratio ~0
  } else {
    float dmax = sqrtf(__uint_as_float(dmaxu[t]));
    if (dmax < 1e-6f) dmax = 1.0f;
    ratio = sqrtf(fmaxf(dist2[t], 1e-24f)) / (dmax + 1e-8f);
  }
  const float stab = 1.0f - 0.3f * c_t[t] + 0.2f * d_t[t];
  const float xi = 1.0f - mu[0] * m_t[t];
  out[t] = fminf(fmaxf(ratio * stab * xi, 0.f), 1.f);
}

extern "C" void kernel_launch(void* const* d_in, const int* in_sizes, int n_in,
                              void* d_out, int out_size, void* d_ws, size_t ws_size,
                              hipStream_t stream) {
  const float* x   = (const float*)d_in[0];
  const float* m_t = (const float*)d_in[1];
  const float* c_t = (const float*)d_in[2];
  const float* d_t = (const float*)d_in[3];
  const float* mu  = (const float*)d_in[4];
  float* out = (float*)d_out;

  float* ws = (float*)d_ws;
  float* invnorm = ws;                                         // [T]
  float* L       = ws + T_;                                    // [T]
  unsigned int* dmaxu = (unsigned int*)(ws + 2 * (size_t)T_);  // [T]
  float* gn2     = ws + 3 * (size_t)T_;                        // [T]
  float* dist2   = ws + 4 * (size_t)T_;                        // [T]
  float* gpart   = ws + 5 * (size_t)T_;                        // [4][T*D] fp32
  unsigned short* hb  = (unsigned short*)(gpart + 4 * (size_t)T_ * D_);
  unsigned short* hbT = hb + (size_t)T_ * D_;
  unsigned short* gb  = hbT + (size_t)T_ * D_;
  unsigned short* W   = gb + (size_t)T_ * D_;                  // [T*T] bf16

  hipMemsetAsync(L, 0, 2 * (size_t)T_ * sizeof(float), stream);  // L + dmaxu only

  k_prep<<<T_, 256, 0, stream>>>(x, invnorm, hb);
  k_transp<<<dim3(T_ / 32, D_ / 32), 256, 0, stream>>>(hb, hbT);
  k_gemm1<<<528, 256, 0, stream>>>(hb, W, L);
  k_gemm2<<<dim3(32, 7, 4), 256, 0, stream>>>(W, hbT, gpart);
  k_gfin<<<T_, 256, 0, stream>>>(gpart, L, x, invnorm, gb, gn2, dist2);
  k_gemm3<<<528, 256, 0, stream>>>(gb, hb, gn2, dmaxu);
  k_final<<<(T_ + 255) / 256, 256, 0, stream>>>(m_t, c_t, d_t, mu, dist2, dmaxu, out);
}

// Round 7
// 200.443 us; speedup vs baseline: 12.2716x; 1.1469x over previous
//
#include <hip/hip_runtime.h>
#include <math.h>

// SemanticDriftCoeff — bf16 MFMA GEMMs, BK=128 single-buffered chunk loop
// (64 KB LDS, 2 blocks/CU, 7 barrier-drains per block instead of 14),
// XOR-swizzled LDS (0 bank conflicts), atomic-free split-K gemm2.
// ws: floats [0,T) invnorm, [T,2T) L, [2T,3T) dmaxu, [3T,4T) gn2, [4T,5T) dist2,
// [5T, 5T+4*T*D) gpart fp32 (4 K-slices); then ushort hb[T*D], hbT[D*T],
// gb[T*D], W[T*T]. ~114 MB.

#define T_ 4096
#define D_ 896

typedef float f32x4 __attribute__((ext_vector_type(4)));
typedef unsigned short u16x8 __attribute__((ext_vector_type(8)));
typedef __bf16 bf16x8 __attribute__((ext_vector_type(8)));

union V16 { uint4 u; u16x8 v; };

__device__ __forceinline__ u16x8 ld16(const unsigned short* p) {
  V16 x; x.u = *(const uint4*)p; return x.v;
}
__device__ __forceinline__ unsigned short f2bf(float f) {  // RNE float->bf16 bits
  unsigned int u = __float_as_uint(f);
  u += 0x7FFFu + ((u >> 16) & 1u);
  return (unsigned short)(u >> 16);
}
__device__ __forceinline__ float bf2f(unsigned short b) {
  return __uint_as_float(((unsigned int)b) << 16);
}
__device__ __forceinline__ f32x4 mfma16(u16x8 a, u16x8 b, f32x4 c) {
  return __builtin_amdgcn_mfma_f32_16x16x32_bf16(
      __builtin_bit_cast(bf16x8, a), __builtin_bit_cast(bf16x8, b), c, 0, 0, 0);
}

typedef __attribute__((address_space(1))) const void glob_cv;
typedef __attribute__((address_space(3))) void lds_v;
__device__ __forceinline__ void gload16(const void* g, void* l) {
  __builtin_amdgcn_global_load_lds((glob_cv*)g, (lds_v*)l, 16, 0, 0);
}

// Stage a 128x128 bf16 tile (rows at `stride` ushorts) into LDS with XOR
// group swizzle: logical 16B-group pg of row r is fetched from global group
// pg ^ (r & 15). LDS dst stays contiguous in lane order (global_load_lds
// constraint); the permutation is applied to the GLOBAL address.
__device__ __forceinline__ void stage_sw(const unsigned short* __restrict__ g0,
                                         int stride, unsigned short* lds0, int tid) {
  #pragma unroll
  for (int it = 0; it < 8; ++it) {
    const int e = it * 256 + tid;        // 16B unit index 0..2047
    const int row = e >> 4, pg = e & 15;
    const int gg = pg ^ (row & 15);      // logical group fetched into physical slot
    gload16(g0 + (size_t)row * stride + gg * 8, lds0 + e * 8);
  }
}

// One 128-deep K-chunk of 128x128 MFMA work from swizzled LDS tiles.
// Rows are 128 ushorts (256 B); frag group for k-offset kk*32+quad*8 is
// (kk*4+quad) ^ (row&15) — 16 lanes hit 16 distinct 16B groups: conflict-free.
__device__ __forceinline__ void mfma_chunk(const unsigned short* As,
    const unsigned short* Bs, int wm, int wn, int tcol, int quad, f32x4 acc[4][4]) {
  const int sx = tcol & 15;              // row&15 == tcol&15 for all frag rows
  #pragma unroll
  for (int kk = 0; kk < 4; ++kk) {
    u16x8 af[4], bf[4];
    const int go = ((kk * 4 + quad) ^ sx) * 8;
    #pragma unroll
    for (int mi = 0; mi < 4; ++mi)
      af[mi] = ld16(&As[(wm * 64 + mi * 16 + tcol) * 128 + go]);
    #pragma unroll
    for (int ni = 0; ni < 4; ++ni)
      bf[ni] = ld16(&Bs[(wn * 64 + ni * 16 + tcol) * 128 + go]);
    #pragma unroll
    for (int mi = 0; mi < 4; ++mi)
      #pragma unroll
      for (int ni = 0; ni < 4; ++ni)
        acc[mi][ni] = mfma16(af[mi], bf[ni], acc[mi][ni]);
  }
}

// triangular decode: b -> (ti, sj), sj <= ti
__device__ __forceinline__ void tri_decode(int b, int& ti, int& sj) {
  ti = (int)((sqrtf(8.0f * (float)b + 1.0f) - 1.0f) * 0.5f);
  while ((ti + 1) * (ti + 2) / 2 <= b) ++ti;
  while (ti * (ti + 1) / 2 > b) --ti;
  sj = b - ti * (ti + 1) / 2;
}

// ---------- prep: invnorm + bf16 normalized rows ----------
__global__ __launch_bounds__(256) void k_prep(const float* __restrict__ x,
    float* __restrict__ invnorm, unsigned short* __restrict__ hb) {
  const int t = (int)blockIdx.x, tid = (int)threadIdx.x;
  const int c = tid * 4;
  float4 v = make_float4(0.f, 0.f, 0.f, 0.f);
  float s = 0.f;
  if (c < D_) {
    v = *(const float4*)(x + (size_t)t * D_ + c);
    s = v.x * v.x + v.y * v.y + v.z * v.z + v.w * v.w;
  }
  __shared__ float sb[4];
  __shared__ float sinv;
  #pragma unroll
  for (int off = 32; off > 0; off >>= 1) s += __shfl_down(s, off, 64);
  if ((tid & 63) == 0) sb[tid >> 6] = s;
  __syncthreads();
  if (tid == 0) {
    const float tot = sb[0] + sb[1] + sb[2] + sb[3];
    const float iv = 1.0f / fmaxf(sqrtf(tot), 1e-12f);
    invnorm[t] = iv; sinv = iv;
  }
  __syncthreads();
  if (c < D_) {
    const float iv = sinv;
    *(ushort4*)(hb + (size_t)t * D_ + c) = make_ushort4(
        f2bf(v.x * iv), f2bf(v.y * iv), f2bf(v.z * iv), f2bf(v.w * iv));
  }
}

// ---------- 32x32 bf16 transpose hb -> hbT ----------
__global__ __launch_bounds__(256) void k_transp(const unsigned short* __restrict__ hb,
                                                unsigned short* __restrict__ hbT) {
  __shared__ unsigned short Ts[32][36];
  const int t0 = (int)blockIdx.x * 32, d0 = (int)blockIdx.y * 32;
  const int r = (int)threadIdx.x >> 3, c = ((int)threadIdx.x & 7) * 4;
  const ushort4 v = *(const ushort4*)(hb + (size_t)(t0 + r) * D_ + d0 + c);
  Ts[r][c] = v.x; Ts[r][c + 1] = v.y; Ts[r][c + 2] = v.z; Ts[r][c + 3] = v.w;
  __syncthreads();
  const ushort4 o = make_ushort4(Ts[c][r], Ts[c + 1][r], Ts[c + 2][r], Ts[c + 3][r]);
  *(ushort4*)(hbT + (size_t)(d0 + r) * T_ + t0 + c) = o;
}

// ---------- GEMM1: S = h h^T (528 causal tiles); epilogue W = exp, L = rowsum ----------
__global__ __launch_bounds__(256, 2) void k_gemm1(const unsigned short* __restrict__ hb,
    unsigned short* __restrict__ W, float* __restrict__ L) {
  int ti, sj;
  tri_decode((int)blockIdx.x, ti, sj);
  const int t0 = ti * 128, s0 = sj * 128;
  __shared__ unsigned short As[128 * 128];
  __shared__ unsigned short Bs[128 * 128];
  const int tid = (int)threadIdx.x;
  const int lane = tid & 63, wv = tid >> 6;
  const int wm = wv >> 1, wn = wv & 1;
  const int tcol = lane & 15, quad = lane >> 4;
  f32x4 acc[4][4] = {};
  for (int kc = 0; kc < 7; ++kc) {
    __syncthreads();   // readers done with buffer
    stage_sw(hb + (size_t)t0 * D_ + kc * 128, D_, As, tid);
    stage_sw(hb + (size_t)s0 * D_ + kc * 128, D_, Bs, tid);
    __syncthreads();   // vmcnt(0) drained, tiles ready
    mfma_chunk(As, Bs, wm, wn, tcol, quad, acc);
  }
  #pragma unroll
  for (int mi = 0; mi < 4; ++mi) {
    #pragma unroll
    for (int r = 0; r < 4; ++r) {
      const int t = t0 + wm * 64 + mi * 16 + quad * 4 + r;
      float lsum = 0.f;
      #pragma unroll
      for (int ni = 0; ni < 4; ++ni) {
        const int s = s0 + wn * 64 + ni * 16 + tcol;
        const int dt = t - s;
        float wval = 0.f;
        if (dt >= 0)
          wval = __expf(acc[mi][ni][r] * (__expf(-0.1f * (float)dt) * 0.033407657f));
        const unsigned short wb = f2bf(wval);
        W[(size_t)t * T_ + s] = wb;
        lsum += bf2f(wb);
      }
      lsum += __shfl_xor(lsum, 1, 64);
      lsum += __shfl_xor(lsum, 2, 64);
      lsum += __shfl_xor(lsum, 4, 64);
      lsum += __shfl_xor(lsum, 8, 64);
      if (tcol == 0) atomicAdd(&L[t], lsum);
    }
  }
}

// ---------- GEMM2 (split-K=4, atomic-free): gpart[z][t][d] = sum_s W[t][s] hbT[d][s] ----------
__global__ __launch_bounds__(256, 2) void k_gemm2(const unsigned short* __restrict__ W,
    const unsigned short* __restrict__ hbT, float* __restrict__ gpart) {
  const int tj = (int)blockIdx.x, dj = (int)blockIdx.y, z = (int)blockIdx.z;
  const int nk = tj + 1;                // causal 128-chunks: s < t0+128
  const int k0 = z * 8;
  if (k0 >= nk) return;
  const int k1 = min(k0 + 8, nk);
  const int t0 = tj * 128, d0 = dj * 128;
  __shared__ unsigned short As[128 * 128];
  __shared__ unsigned short Bs[128 * 128];
  const int tid = (int)threadIdx.x;
  const int lane = tid & 63, wv = tid >> 6;
  const int wm = wv >> 1, wn = wv & 1;
  const int tcol = lane & 15, quad = lane >> 4;
  f32x4 acc[4][4] = {};
  for (int kc = k0; kc < k1; ++kc) {
    __syncthreads();
    stage_sw(W + (size_t)t0 * T_ + kc * 128, T_, As, tid);    // A[m=t][k=s]
    stage_sw(hbT + (size_t)d0 * T_ + kc * 128, T_, Bs, tid);  // B[n=d][k=s]
    __syncthreads();
    mfma_chunk(As, Bs, wm, wn, tcol, quad, acc);
  }
  float* base = gpart + (size_t)z * T_ * D_;
  #pragma unroll
  for (int mi = 0; mi < 4; ++mi) {
    #pragma unroll
    for (int ni = 0; ni < 4; ++ni) {
      const int t = t0 + wm * 64 + mi * 16 + quad * 4;
      const int d = d0 + wn * 64 + ni * 16 + tcol;
      float* gp = base + (size_t)t * D_ + d;
      gp[0]        = acc[mi][ni][0];
      gp[D_]       = acc[mi][ni][1];
      gp[2 * D_]   = acc[mi][ni][2];
      gp[3 * D_]   = acc[mi][ni][3];
    }
  }
}

// ---------- gfin: g = (sum_z gpart)/L; gb = bf16(g); gn2; dist2 ----------
__global__ __launch_bounds__(256) void k_gfin(const float* __restrict__ gpart,
    const float* __restrict__ L, const float* __restrict__ x,
    const float* __restrict__ invnorm, unsigned short* __restrict__ gb,
    float* __restrict__ gn2, float* __restrict__ dist2) {
  const int t = (int)blockIdx.x, tid = (int)threadIdx.x;
  const int tj = t >> 7;
  const int nz = (tj + 8) >> 3;          // ceil((tj+1)/8) valid K-slices
  const float invL = 1.0f / L[t];
  const float inr = invnorm[t];
  float sg = 0.f, sd = 0.f;
  const int c = tid * 4;
  if (c < D_) {
    float4 gv = make_float4(0.f, 0.f, 0.f, 0.f);
    for (int z = 0; z < nz; ++z) {
      const float4 p = *(const float4*)(gpart + (size_t)z * T_ * D_ + (size_t)t * D_ + c);
      gv.x += p.x; gv.y += p.y; gv.z += p.z; gv.w += p.w;
    }
    gv.x *= invL; gv.y *= invL; gv.z *= invL; gv.w *= invL;
    *(ushort4*)(gb + (size_t)t * D_ + c) =
        make_ushort4(f2bf(gv.x), f2bf(gv.y), f2bf(gv.z), f2bf(gv.w));
    const float4 hv = *(const float4*)(x + (size_t)t * D_ + c);
    const float e0 = hv.x * inr - gv.x, e1 = hv.y * inr - gv.y;
    const float e2 = hv.z * inr - gv.z, e3 = hv.w * inr - gv.w;
    sg = gv.x * gv.x + gv.y * gv.y + gv.z * gv.z + gv.w * gv.w;
    sd = e0 * e0 + e1 * e1 + e2 * e2 + e3 * e3;
  }
  __shared__ float sb1[4], sb2[4];
  #pragma unroll
  for (int off = 32; off > 0; off >>= 1) {
    sg += __shfl_down(sg, off, 64);
    sd += __shfl_down(sd, off, 64);
  }
  if ((tid & 63) == 0) { sb1[tid >> 6] = sg; sb2[tid >> 6] = sd; }
  __syncthreads();
  if (tid == 0) {
    gn2[t]   = sb1[0] + sb1[1] + sb1[2] + sb1[3];
    dist2[t] = sb2[0] + sb2[1] + sb2[2] + sb2[3];
  }
}

// ---------- GEMM3: cross = g h^T (528 causal tiles); causal row-max of d2 ----------
__global__ __launch_bounds__(256, 2) void k_gemm3(const unsigned short* __restrict__ gb,
    const unsigned short* __restrict__ hb, const float* __restrict__ gn2,
    unsigned int* __restrict__ dmaxu) {
  int ti, sj;
  tri_decode((int)blockIdx.x, ti, sj);
  const int t0 = ti * 128, s0 = sj * 128;
  __shared__ unsigned short As[128 * 128];
  __shared__ unsigned short Bs[128 * 128];
  const int tid = (int)threadIdx.x;
  const int lane = tid & 63, wv = tid >> 6;
  const int wm = wv >> 1, wn = wv & 1;
  const int tcol = lane & 15, quad = lane >> 4;
  f32x4 acc[4][4] = {};
  for (int kc = 0; kc < 7; ++kc) {
    __syncthreads();
    stage_sw(gb + (size_t)t0 * D_ + kc * 128, D_, As, tid);
    stage_sw(hb + (size_t)s0 * D_ + kc * 128, D_, Bs, tid);
    __syncthreads();
    mfma_chunk(As, Bs, wm, wn, tcol, quad, acc);
  }
  #pragma unroll
  for (int mi = 0; mi < 4; ++mi) {
    #pragma unroll
    for (int r = 0; r < 4; ++r) {
      const int t = t0 + wm * 64 + mi * 16 + quad * 4 + r;
      const float gn = gn2[t];
      float m2 = 0.f;
      #pragma unroll
      for (int ni = 0; ni < 4; ++ni) {
        const int s = s0 + wn * 64 + ni * 16 + tcol;
        if (t - s >= 0)
          m2 = fmaxf(m2, fmaxf(1.0f - 2.0f * acc[mi][ni][r] + gn, 1e-24f));
      }
      m2 = fmaxf(m2, __shfl_xor(m2, 1, 64));
      m2 = fmaxf(m2, __shfl_xor(m2, 2, 64));
      m2 = fmaxf(m2, __shfl_xor(m2, 4, 64));
      m2 = fmaxf(m2, __shfl_xor(m2, 8, 64));
      if (tcol == 0) atomicMax(&dmaxu[t], __float_as_uint(m2));
    }
  }
}

__global__ __launch_bounds__(256) void k_final(const float* __restrict__ m_t,
    const float* __restrict__ c_t, const float* __restrict__ d_t,
    const float* __restrict__ mu, const float* __restrict__ dist2,
    const unsigned int* __restrict__ dmaxu, float* __restrict__ out) {
  const int t = (int)blockIdx.x * 256 + (int)threadIdx.x;
  if (t >= T_) return;
  float ratio;
  if (t == 0) {
    ratio = 0.f;  // ref: dist~1e-12, dist_max<1e-6 -> 1.0 => ratio ~0
  } else {
    float dmax = sqrtf(__uint_as_float(dmaxu[t]));
    if (dmax < 1e-6f) dmax = 1.0f;
    ratio = sqrtf(fmaxf(dist2[t], 1e-24f)) / (dmax + 1e-8f);
  }
  const float stab = 1.0f - 0.3f * c_t[t] + 0.2f * d_t[t];
  const float xi = 1.0f - mu[0] * m_t[t];
  out[t] = fminf(fmaxf(ratio * stab * xi, 0.f), 1.f);
}

extern "C" void kernel_launch(void* const* d_in, const int* in_sizes, int n_in,
                              void* d_out, int out_size, void* d_ws, size_t ws_size,
                              hipStream_t stream) {
  const float* x   = (const float*)d_in[0];
  const float* m_t = (const float*)d_in[1];
  const float* c_t = (const float*)d_in[2];
  const float* d_t = (const float*)d_in[3];
  const float* mu  = (const float*)d_in[4];
  float* out = (float*)d_out;

  float* ws = (float*)d_ws;
  float* invnorm = ws;                                         // [T]
  float* L       = ws + T_;                                    // [T]
  unsigned int* dmaxu = (unsigned int*)(ws + 2 * (size_t)T_);  // [T]
  float* gn2     = ws + 3 * (size_t)T_;                        // [T]
  float* dist2   = ws + 4 * (size_t)T_;                        // [T]
  float* gpart   = ws + 5 * (size_t)T_;                        // [4][T*D] fp32
  unsigned short* hb  = (unsigned short*)(gpart + 4 * (size_t)T_ * D_);
  unsigned short* hbT = hb + (size_t)T_ * D_;
  unsigned short* gb  = hbT + (size_t)T_ * D_;
  unsigned short* W   = gb + (size_t)T_ * D_;                  // [T*T] bf16

  hipMemsetAsync(L, 0, 2 * (size_t)T_ * sizeof(float), stream);  // L + dmaxu only

  k_prep<<<T_, 256, 0, stream>>>(x, invnorm, hb);
  k_transp<<<dim3(T_ / 32, D_ / 32), 256, 0, stream>>>(hb, hbT);
  k_gemm1<<<528, 256, 0, stream>>>(hb, W, L);
  k_gemm2<<<dim3(32, 7, 4), 256, 0, stream>>>(W, hbT, gpart);
  k_gfin<<<T_, 256, 0, stream>>>(gpart, L, x, invnorm, gb, gn2, dist2);
  k_gemm3<<<528, 256, 0, stream>>>(gb, hb, gn2, dmaxu);
  k_final<<<(T_ + 255) / 256, 256, 0, stream>>>(m_t, c_t, d_t, mu, dist2, dmaxu, out);
}